// Round 11
// baseline (152.513 us; speedup 1.0000x reference)
//
#include <hip/hip_runtime.h>
#include <hip/hip_bf16.h>
#include <hip/hip_fp8.h>

typedef __bf16 bf16x8 __attribute__((ext_vector_type(8)));
typedef __bf16 bf16x4 __attribute__((ext_vector_type(4)));
typedef float f32x4 __attribute__((ext_vector_type(4)));
typedef unsigned int u32;
typedef __attribute__((address_space(3))) u32 lds_u32_t;
typedef __attribute__((address_space(1))) u32 glb_u32_t;

#define MROWS 8192      // B*S
#define DDIM 1024
#define EDIM 2048
#define HQK 256         // h buffer holds only q|k columns

#define S_BAR() asm volatile("s_barrier" ::: "memory")
#define S_VM0() asm volatile("s_waitcnt vmcnt(0)" ::: "memory")
#define SCHED_PIN() __builtin_amdgcn_sched_barrier(0)

__device__ __forceinline__ void async16(const void* g, void* l) {
  __builtin_amdgcn_global_load_lds((const glb_u32_t*)g, (lds_u32_t*)l, 16, 0, 0);
}

__device__ __forceinline__ u32 pack4_e4m3(float f0, float f1, float f2, float f3) {
  __hip_fp8_e4m3 a(f0), b(f1), c(f2), d(f3);
  return (u32)a.__x | ((u32)b.__x << 8) | ((u32)c.__x << 16) | ((u32)d.__x << 24);
}

// ---------------- LayerNorm + bf16 cast + fp8 cast ----------------
__global__ __launch_bounds__(256) void ln_kernel(const float* __restrict__ x,
                                                 const float* __restrict__ wgt,
                                                 __bf16* __restrict__ xn,
                                                 u32* __restrict__ xn8) {
  const int row = blockIdx.x;
  const int t = threadIdx.x;
  const float4 v = ((const float4*)(x + (size_t)row * DDIM))[t];
  float s = v.x + v.y + v.z + v.w;
  float ss = v.x * v.x + v.y * v.y + v.z * v.z + v.w * v.w;
  #pragma unroll
  for (int o = 32; o > 0; o >>= 1) {
    s += __shfl_down(s, o);
    ss += __shfl_down(ss, o);
  }
  __shared__ float red[8];
  const int lane = t & 63, wv = t >> 6;
  if (lane == 0) { red[wv] = s; red[4 + wv] = ss; }
  __syncthreads();
  s = red[0] + red[1] + red[2] + red[3];
  ss = red[4] + red[5] + red[6] + red[7];
  const float mu = s * (1.0f / 1024.0f);
  const float rstd = rsqrtf(ss * (1.0f / 1024.0f) - mu * mu + 1e-5f);
  const float4 w4 = ((const float4*)wgt)[t];
  const float f0 = (v.x - mu) * rstd * w4.x;
  const float f1 = (v.y - mu) * rstd * w4.y;
  const float f2 = (v.z - mu) * rstd * w4.z;
  const float f3 = (v.w - mu) * rstd * w4.w;
  bf16x4 o;
  o[0] = (__bf16)f0; o[1] = (__bf16)f1; o[2] = (__bf16)f2; o[3] = (__bf16)f3;
  ((bf16x4*)(xn + (size_t)row * DDIM))[t] = o;
  xn8[row * 256 + t] = pack4_e4m3(f0, f1, f2, f3);
}

// ---------------- fp32 -> bf16 weight cast ----------------
__global__ __launch_bounds__(256) void cast_kernel(const float* __restrict__ src,
                                                   __bf16* __restrict__ dst, int n4) {
  const int i = blockIdx.x * 256 + threadIdx.x;
  if (i < n4) {
    const float4 v = ((const float4*)src)[i];
    bf16x4 o;
    o[0] = (__bf16)v.x; o[1] = (__bf16)v.y; o[2] = (__bf16)v.z; o[3] = (__bf16)v.w;
    ((bf16x4*)dst)[i] = o;
  }
}

// ---------------- fp32 -> fp8 weight cast (pre-scaled) ----------------
__global__ __launch_bounds__(256) void cast8_kernel(const float* __restrict__ src,
                                                    u32* __restrict__ dst, int n4, float scale) {
  const int i = blockIdx.x * 256 + threadIdx.x;
  if (i < n4) {
    const float4 v = ((const float4*)src)[i];
    dst[i] = pack4_e4m3(v.x * scale, v.y * scale, v.z * scale, v.w * scale);
  }
}

// ------ fp32 -> fp8 interleaved expand-weight cast (lin/pre frag pairs) ------
__global__ __launch_bounds__(256) void cast8i_kernel(const float* __restrict__ src,
                                                     u32* __restrict__ dst) {
  const int i = blockIdx.x * 256 + threadIdx.x;   // 4096*256
  const int rp = i >> 8, k4 = i & 255;
  const int c = ((rp >> 5) << 4) | (rp & 15);
  const int pre = (rp >> 4) & 1;
  const float4 v = *(const float4*)(src + ((size_t)(pre * 2048 + c)) * 1024 + k4 * 4);
  dst[i] = pack4_e4m3(v.x * 16.0f, v.y * 16.0f, v.z * 16.0f, v.w * 16.0f);
}

// ------------- small m97-style bf16 GEMM (skinny q/k columns) -------------
__global__ __launch_bounds__(256) void gemm_bt(const __bf16* __restrict__ A,
                                               const __bf16* __restrict__ Bt,
                                               __bf16* __restrict__ Cout,
                                               int Ndim, int Kdim, int coff) {
  __shared__ __bf16 As[128 * 32];
  __shared__ __bf16 Bs[128 * 32];
  const int t = threadIdx.x;
  const int lane = t & 63;
  const int w = t >> 6;
  const int wm = w >> 1, wn = w & 1;
  const int m0 = blockIdx.x * 128;
  const int n0 = blockIdx.y * 128;

  f32x4 acc[4][4] = {};

  const int cA = w * 2;
  const int sr = cA * 16 + (lane >> 2);
  const int sc = (lane & 3) * 8;
  const __bf16* gA0 = A + (size_t)(m0 + sr) * Kdim + sc;
  const __bf16* gA1 = A + (size_t)(m0 + sr + 16) * Kdim + sc;
  const __bf16* gB0 = Bt + (size_t)(n0 + sr) * Kdim + sc;
  const __bf16* gB1 = Bt + (size_t)(n0 + sr + 16) * Kdim + sc;
  __bf16* lA0 = As + cA * 512;
  __bf16* lA1 = As + (cA + 1) * 512;
  __bf16* lB0 = Bs + cA * 512;
  __bf16* lB1 = Bs + (cA + 1) * 512;

  const int lr = lane & 15;
  const int lk = (lane >> 4) * 8;
  const int nk = Kdim >> 5;

  for (int kt = 0; kt < nk; ++kt) {
    __syncthreads();
    const int ko = kt * 32;
    async16(gA0 + ko, lA0);
    async16(gA1 + ko, lA1);
    async16(gB0 + ko, lB0);
    async16(gB1 + ko, lB1);
    __syncthreads();
    bf16x8 a[4], b[4];
    #pragma unroll
    for (int i = 0; i < 4; ++i)
      a[i] = *(const bf16x8*)&As[(wm * 64 + i * 16 + lr) * 32 + lk];
    #pragma unroll
    for (int i = 0; i < 4; ++i)
      b[i] = *(const bf16x8*)&Bs[(wn * 64 + i * 16 + lr) * 32 + lk];
    #pragma unroll
    for (int i = 0; i < 4; ++i)
      #pragma unroll
      for (int j = 0; j < 4; ++j)
        acc[i][j] = __builtin_amdgcn_mfma_f32_16x16x32_bf16(a[i], b[j], acc[i][j], 0, 0, 0);
  }

  #pragma unroll
  for (int i = 0; i < 4; ++i) {
    const int rbase = m0 + wm * 64 + i * 16 + ((lane >> 4) << 2);
    #pragma unroll
    for (int j = 0; j < 4; ++j) {
      const int col = coff + n0 + wn * 64 + j * 16 + (lane & 15);
      #pragma unroll
      for (int r = 0; r < 4; ++r)
        Cout[(size_t)(rbase + r) * Ndim + col] = (__bf16)acc[i][j][r];
    }
  }
}

// ------- fp8 GEMM + fused GEGLU epilogue, TRANSPOSED output -------
// BM=128, BN=256 (interleaved lin/pre 16-col frags), BK=64.
// mfma(A=weight frag, B=xn frag) -> C^T: reg r = 4 consecutive output cols
// -> geglu in fp32 -> one u32 (4x fp8) store per (pair, mf).
__global__ __launch_bounds__(512, 4) void gemm1glu(const char* __restrict__ A8,
                                                   const char* __restrict__ B8,
                                                   char* __restrict__ fused8,
                                                   char* __restrict__ vbuf8) {
  constexpr int ASZ = 128 * 64;
  constexpr int BSZ = 256 * 64;
  constexpr int Kdim = 1024;
  __shared__ alignas(16) char As[2 * ASZ];
  __shared__ alignas(16) char Bs[2 * BSZ];

  const int tid = threadIdx.x;
  const int lane = tid & 63;
  const int w = tid >> 6;
  const int wm = w >> 2, wn = w & 3;

  const int qq = gridDim.x >> 3;
  const int wgid = (blockIdx.x & 7) * qq + (blockIdx.x >> 3);
  const int m0 = (wgid / 16) * 128;
  const int nblk = wgid % 16;
  const int n0r = nblk * 256;          // weight-row base

  f32x4 acc[4][4] = {};                // acc[nf][mf] (transposed)

  const int rowS = (tid >> 2) & 127;
  const int uS = tid & 3;
  const int luS = uS ^ ((rowS >> 1) & 3);
  const char* gA = A8 + (size_t)(m0 + rowS) * Kdim + luS * 16;
  const char* gB = B8 + (size_t)(n0r + rowS) * Kdim + luS * 16;
  char* lA = (char*)As;
  char* lB = (char*)Bs;

  const int lr = lane & 15;
  const int hi = lane >> 4;
  const int sw = (lr >> 1) & 3;
  const int kof0 = ((((hi >> 1)) ^ sw) << 4) + (hi & 1) * 8;
  const int kof1 = (((2 + (hi >> 1)) ^ sw) << 4) + (hi & 1) * 8;
  const int rowA = (wm * 64 + lr) * 64;
  const int rowB = (wn * 64 + lr) * 64;
  const int NT = Kdim >> 6;

  async16(gA, lA + tid * 16);
  async16(gB, lB + tid * 16);
  async16(gB + (size_t)128 * Kdim, lB + 8192 + tid * 16);
  S_VM0();
  S_BAR();

  for (int t = 0; t < NT; ++t) {
    const int buf = t & 1;
    const char* pA = lA + buf * ASZ + rowA;
    const char* pB = lB + buf * BSZ + rowB;

    long a0[4], b0[4], a1[4], b1[4];
    #pragma unroll
    for (int ni = 0; ni < 4; ++ni) b0[ni] = *(const long*)(pB + ni * 1024 + kof0);
    #pragma unroll
    for (int mi = 0; mi < 4; ++mi) a0[mi] = *(const long*)(pA + mi * 1024 + kof0);
    SCHED_PIN();
    #pragma unroll
    for (int ni = 0; ni < 4; ++ni) b1[ni] = *(const long*)(pB + ni * 1024 + kof1);
    #pragma unroll
    for (int mi = 0; mi < 4; ++mi) a1[mi] = *(const long*)(pA + mi * 1024 + kof1);
    SCHED_PIN();
    if (t + 1 < NT) {
      const char* gAt = gA + (size_t)(t + 1) * 64;
      const char* gBt = gB + (size_t)(t + 1) * 64;
      char* lAd = lA + (buf ^ 1) * ASZ + tid * 16;
      char* lBd = lB + (buf ^ 1) * BSZ + tid * 16;
      async16(gAt, lAd);
      async16(gBt, lBd);
      async16(gBt + (size_t)128 * Kdim, lBd + 8192);
    }
    SCHED_PIN();
    __builtin_amdgcn_s_setprio(1);
    #pragma unroll
    for (int ni = 0; ni < 4; ++ni)
      #pragma unroll
      for (int mi = 0; mi < 4; ++mi)
        acc[ni][mi] = __builtin_amdgcn_mfma_f32_16x16x32_fp8_fp8(b0[ni], a0[mi], acc[ni][mi], 0, 0, 0);
    __builtin_amdgcn_s_setprio(0);
    SCHED_PIN();
    __builtin_amdgcn_s_setprio(1);
    #pragma unroll
    for (int ni = 0; ni < 4; ++ni)
      #pragma unroll
      for (int mi = 0; mi < 4; ++mi)
        acc[ni][mi] = __builtin_amdgcn_mfma_f32_16x16x32_fp8_fp8(b1[ni], a1[mi], acc[ni][mi], 0, 0, 0);
    __builtin_amdgcn_s_setprio(0);
    SCHED_PIN();
    if (t + 1 < NT) S_VM0();
    S_BAR();
  }

  // fused GEGLU epilogue (transposed): lane holds 4 consecutive output cols.
  // frag nf: weight rows (n0r + (wn*4+nf)*16 + hi*4 + r) -> pair p = nf>>1,
  // output col cb = (nblk*8 + wn*2 + p)*16 + hi*4 + r ; m = m0+wm*64+mf*16+(lane&15)
  const bool isv = nblk >= 8;
  #pragma unroll
  for (int p = 0; p < 2; ++p) {
    const int cb = (nblk * 8 + wn * 2 + p) * 16 + hi * 4;
    #pragma unroll
    for (int mf = 0; mf < 4; ++mf) {
      const int m = m0 + wm * 64 + mf * 16 + (lane & 15);
      float g[4];
      #pragma unroll
      for (int r = 0; r < 4; ++r) {
        const float l = acc[2 * p][mf][r] * 0.0625f;
        const float q = acc[2 * p + 1][mf][r] * 0.0625f;
        g[r] = l * 0.5f * q * (1.0f + erff(q * 0.70710678118f));
      }
      const u32 pk = pack4_e4m3(g[0], g[1], g[2], g[3]);
      if (isv) *(u32*)&vbuf8[(size_t)m * 1024 + (cb - 1024)] = pk;
      else     *(u32*)&fused8[(size_t)m * EDIM + cb] = pk;
    }
  }
}

// ---------------- fp8 project GEMM, BM=128 BN=128 BK=128 ----------------
// 8-unit XOR swizzle, 64KB LDS -> 2 blocks/CU, grid 512 = 1.0 round.
__global__ __launch_bounds__(512, 2) void gemmproj(const char* __restrict__ A8,
                                                   const char* __restrict__ B8,
                                                   float* __restrict__ out,
                                                   const float* __restrict__ resid,
                                                   float scl) {
  constexpr int ASZ = 128 * 128;   // 16KB
  constexpr int BSZ = 128 * 128;   // 16KB
  constexpr int Kdim = 2048;
  __shared__ alignas(16) char As[2 * ASZ];
  __shared__ alignas(16) char Bs[2 * BSZ];

  const int tid = threadIdx.x;
  const int lane = tid & 63;
  const int w = tid >> 6;
  const int wm = w >> 2, wn = w & 3;

  const int qq = gridDim.x >> 3;
  const int wgid = (blockIdx.x & 7) * qq + (blockIdx.x >> 3);
  const int m0 = (wgid / 8) * 128;
  const int n0 = (wgid % 8) * 128;

  f32x4 acc[4][2] = {};

  const int rowS = tid >> 3;           // 0..63
  const int uS = tid & 7;
  const int luS = uS ^ (rowS & 7);
  const char* gA = A8 + (size_t)(m0 + rowS) * Kdim + luS * 16;
  const char* gB = B8 + (size_t)(n0 + rowS) * Kdim + luS * 16;
  char* lA = (char*)As;
  char* lB = (char*)Bs;

  const int lr = lane & 15;
  const int hi = lane >> 4;
  int kof[4];
  #pragma unroll
  for (int kq = 0; kq < 4; ++kq)
    kof[kq] = (((kq * 2 + (hi >> 1)) ^ (lr & 7)) << 4) + (hi & 1) * 8;
  const int rowA = (wm * 64 + lr) * 128;
  const int rowB = (wn * 32 + lr) * 128;
  const int NT = Kdim >> 7;            // 16

  // prologue: stage tile 0 (A rows 0-63,64-127; B rows 0-63,64-127)
  async16(gA, lA + tid * 16);
  async16(gA + (size_t)64 * Kdim, lA + 8192 + tid * 16);
  async16(gB, lB + tid * 16);
  async16(gB + (size_t)64 * Kdim, lB + 8192 + tid * 16);
  S_VM0();
  S_BAR();

  for (int t = 0; t < NT; ++t) {
    const int buf = t & 1;
    const char* pA = lA + buf * ASZ + rowA;
    const char* pB = lB + buf * BSZ + rowB;

    long a[4][4], bb[4][2];
    #pragma unroll
    for (int kq = 0; kq < 4; ++kq) {
      #pragma unroll
      for (int ni = 0; ni < 2; ++ni) bb[kq][ni] = *(const long*)(pB + ni * 2048 + kof[kq]);
      #pragma unroll
      for (int mi = 0; mi < 4; ++mi) a[kq][mi] = *(const long*)(pA + mi * 2048 + kof[kq]);
    }
    SCHED_PIN();
    if (t + 1 < NT) {
      const char* gAt = gA + (size_t)(t + 1) * 128;
      const char* gBt = gB + (size_t)(t + 1) * 128;
      char* lAd = lA + (buf ^ 1) * ASZ + tid * 16;
      char* lBd = lB + (buf ^ 1) * BSZ + tid * 16;
      async16(gAt, lAd);
      async16(gAt + (size_t)64 * Kdim, lAd + 8192);
      async16(gBt, lBd);
      async16(gBt + (size_t)64 * Kdim, lBd + 8192);
    }
    SCHED_PIN();
    #pragma unroll
    for (int kq = 0; kq < 4; ++kq) {
      __builtin_amdgcn_s_setprio(1);
      #pragma unroll
      for (int mi = 0; mi < 4; ++mi)
        #pragma unroll
        for (int ni = 0; ni < 2; ++ni)
          acc[mi][ni] = __builtin_amdgcn_mfma_f32_16x16x32_fp8_fp8(a[kq][mi], bb[kq][ni], acc[mi][ni], 0, 0, 0);
      __builtin_amdgcn_s_setprio(0);
      SCHED_PIN();
    }
    if (t + 1 < NT) S_VM0();
    S_BAR();
  }

  #pragma unroll
  for (int mi = 0; mi < 4; ++mi) {
    const int rbase = m0 + wm * 64 + mi * 16 + (hi << 2);
    #pragma unroll
    for (int ni = 0; ni < 2; ++ni) {
      const int col = n0 + wn * 32 + ni * 16 + (lane & 15);
      #pragma unroll
      for (int r = 0; r < 4; ++r) {
        const size_t off = (size_t)(rbase + r) * DDIM + col;
        out[off] = resid[off] + acc[mi][ni][r] * scl;
      }
    }
  }
}

// --------- fp8 V transpose: vbuf8[8192][1024] -> vTb[b][h][sblk16][d256][s64] ------
__global__ __launch_bounds__(256) void vT8_kernel(const char* __restrict__ vbuf8,
                                                  char* __restrict__ vTb) {
  const int blk = blockIdx.x;          // 512
  const int sblk = blk & 15;
  const int head = (blk >> 4) & 3;
  const int b = blk >> 6;
  const int t = threadIdx.x;
  __shared__ u32 vt[64][66];

  const int s_l = t >> 2, q4 = t & 3;
  const uint4* src = (const uint4*)&vbuf8[(size_t)(b * 1024 + sblk * 64 + s_l) * 1024 +
                                          head * 256 + q4 * 64];
  #pragma unroll
  for (int c = 0; c < 4; ++c) {
    const uint4 ww = src[c];
    vt[s_l][q4 * 16 + c * 4 + 0] = ww.x;
    vt[s_l][q4 * 16 + c * 4 + 1] = ww.y;
    vt[s_l][q4 * 16 + c * 4 + 2] = ww.z;
    vt[s_l][q4 * 16 + c * 4 + 3] = ww.w;
  }
  __syncthreads();
  const int d = t;
  const int wsel = (d & 3) * 8;
  char* dst = vTb + (((size_t)(b * 4 + head) * 16 + sblk) * 256 + d) * 64;
  #pragma unroll
  for (int c = 0; c < 4; ++c) {
    u32 wo[4];
    #pragma unroll
    for (int k = 0; k < 4; ++k) {
      const int s0 = c * 16 + k * 4;
      const u32 r0 = vt[s0 + 0][d >> 2];
      const u32 r1 = vt[s0 + 1][d >> 2];
      const u32 r2 = vt[s0 + 2][d >> 2];
      const u32 r3 = vt[s0 + 3][d >> 2];
      wo[k] = ((r0 >> wsel) & 0xffu) | (((r1 >> wsel) & 0xffu) << 8) |
              (((r2 >> wsel) & 0xffu) << 16) | (((r3 >> wsel) & 0xffu) << 24);
    }
    *(uint4*)(dst + c * 16) = make_uint4(wo[0], wo[1], wo[2], wo[3]);
  }
}

// ------------- MFMA sliding-window attention (W=32) -------------
__global__ __launch_bounds__(256, 2) void attn_mfma(const __bf16* __restrict__ h,
                                                    const char* __restrict__ vTb,
                                                    char* __restrict__ fused8,
                                                    const float* __restrict__ pbm) {
  const int blk = blockIdx.x;          // 256
  const int qblk = blk & 7;
  const int head = (blk >> 3) & 3;
  const int b = blk >> 5;
  const int tid = threadIdx.x;
  const int lane = tid & 63;
  const int w = tid >> 6;
  __shared__ char vt[256 * 176];
  __shared__ char pl[4][32 * 80];

  const float p = pbm[0];
  const float sp = (p > 20.0f) ? p : log1pf(expf(p));

  {
    const int m = qblk * 2;
    const char* base = vTb + ((size_t)(b * 4 + head) * 16) * 16384;
    #pragma unroll
    for (int it = 0; it < 11; ++it) {
      const int U = it * 256 + tid;
      const int d = U / 11;
      const int slot = U - d * 11;
      int sb, so;
      if (slot >= 10)      { sb = m; so = 0; }
      else if (slot < 2)   { sb = m - 1; so = 32 + slot * 16; }
      else if (slot < 6)   { sb = m; so = (slot - 2) * 16; }
      else                 { sb = m + 1; so = (slot - 6) * 16; }
      if (sb < 0) sb = 0;
      async16(base + ((size_t)sb * 256 + d) * 64 + so, vt + U * 16);
    }
  }

  const int col = lane & 15;
  const int hi = lane >> 4;
  const int qb = qblk * 128 + w * 32;
  const int kb = qb - 32;

  f32x4 sc[4][2] = {};
  bf16x8 afr[4], bfr[2];
  #pragma unroll
  for (int mf = 0; mf < 4; ++mf) {
    int key = kb + mf * 16 + col;
    if (key < 0) key = 0;
    afr[mf] = *(const bf16x8*)&h[(size_t)(b * 1024 + key) * HQK + 128 + head * 32 + hi * 8];
  }
  #pragma unroll
  for (int nf = 0; nf < 2; ++nf)
    bfr[nf] = *(const bf16x8*)&h[(size_t)(b * 1024 + qb + nf * 16 + col) * HQK + head * 32 + hi * 8];
  #pragma unroll
  for (int mf = 0; mf < 4; ++mf)
    #pragma unroll
    for (int nf = 0; nf < 2; ++nf)
      sc[mf][nf] = __builtin_amdgcn_mfma_f32_16x16x32_bf16(afr[mf], bfr[nf], sc[mf][nf], 0, 0, 0);

  #pragma unroll
  for (int nf = 0; nf < 2; ++nf) {
    #pragma unroll
    for (int mf = 0; mf < 4; ++mf)
      #pragma unroll
      for (int r = 0; r < 4; ++r) {
        const int delta = mf * 16 + hi * 4 + r - nf * 16 - col - 32;
        const int keyabs = kb + mf * 16 + hi * 4 + r;
        const bool valid = (delta <= 0) & (delta >= -31) & (keyabs >= 0);
        sc[mf][nf][r] = valid ? sc[mf][nf][r] * 0.1767766953f + sp * (float)delta : -1e30f;
      }
    float m = -1e30f;
    #pragma unroll
    for (int mf = 0; mf < 4; ++mf)
      #pragma unroll
      for (int r = 0; r < 4; ++r) m = fmaxf(m, sc[mf][nf][r]);
    m = fmaxf(m, __shfl_xor(m, 16));
    m = fmaxf(m, __shfl_xor(m, 32));
    float s = 0.0f;
    #pragma unroll
    for (int mf = 0; mf < 4; ++mf)
      #pragma unroll
      for (int r = 0; r < 4; ++r) {
        const float e = __expf(sc[mf][nf][r] - m);
        sc[mf][nf][r] = e;
        s += e;
      }
    s += __shfl_xor(s, 16);
    s += __shfl_xor(s, 32);
    const float inv = 1.0f / s;
    #pragma unroll
    for (int mf = 0; mf < 4; ++mf) {
      const u32 pk = pack4_e4m3(sc[mf][nf][0] * inv, sc[mf][nf][1] * inv,
                                sc[mf][nf][2] * inv, sc[mf][nf][3] * inv);
      *(u32*)&pl[w][(nf * 16 + col) * 80 + mf * 16 + hi * 4] = pk;
    }
  }

  __syncthreads();

  const char* ppl = pl[w];
  const int kloc = w * 32;
  f32x4 ao[16][2] = {};
  #pragma unroll
  for (int kf = 0; kf < 2; ++kf) {
    long bfrag[2];
    #pragma unroll
    for (int nf = 0; nf < 2; ++nf)
      bfrag[nf] = *(const long*)&ppl[(nf * 16 + col) * 80 + kf * 32 + hi * 8];
    #pragma unroll
    for (int mf = 0; mf < 16; ++mf) {
      const long af = *(const long*)&vt[(mf * 16 + col) * 176 + kloc + kf * 32 + hi * 8];
      #pragma unroll
      for (int nf = 0; nf < 2; ++nf)
        ao[mf][nf] = __builtin_amdgcn_mfma_f32_16x16x32_fp8_fp8(af, bfrag[nf], ao[mf][nf], 0, 0, 0);
    }
  }

  #pragma unroll
  for (int mf = 0; mf < 16; ++mf)
    #pragma unroll
    for (int nf = 0; nf < 2; ++nf) {
      const u32 pk = pack4_e4m3(ao[mf][nf][0], ao[mf][nf][1], ao[mf][nf][2], ao[mf][nf][3]);
      *(u32*)&fused8[(size_t)(b * 1024 + qb + nf * 16 + col) * EDIM + 1024 +
                     head * 256 + mf * 16 + hi * 4] = pk;
    }
}

// ---------------- host launch ----------------
extern "C" void kernel_launch(void* const* d_in, const int* in_sizes, int n_in,
                              void* d_out, int out_size, void* d_ws, size_t ws_size,
                              hipStream_t stream) {
  const float* x = (const float*)d_in[0];
  const float* norm_w = (const float*)d_in[2];
  const float* expand_w = (const float*)d_in[3];
  const float* project_w = (const float*)d_in[4];
  const float* pbm = (const float*)d_in[5];
  float* out = (float*)d_out;

  char* ws = (char*)d_ws;
  __bf16* xn    = (__bf16*)(ws);                  // 16,777,216
  u32*    xn8   = (u32*)(ws + 16777216);          //  8,388,608
  __bf16* wqk   = (__bf16*)(ws + 25165824);       //    524,288
  char*   wexp8i= (char*)(ws + 25690112);         //  4,194,304 (interleaved, x16)
  char*   wproj8= (char*)(ws + 29884416);         //  2,097,152 (x256)
  __bf16* h     = (__bf16*)(ws + 31981568);       //  4,194,304 (q|k only)
  char*   fused8= (char*)(ws + 36175872);         // 16,777,216
  char*   vbuf8 = (char*)(ws + 52953088);         //  8,388,608
  char*   vTb   = (char*)(ws + 61341696);         //  8,388,608

  ln_kernel<<<MROWS, 256, 0, stream>>>(x, norm_w, xn, xn8);
  cast_kernel<<<256, 256, 0, stream>>>(expand_w, wqk, 65536);
  cast8i_kernel<<<4096, 256, 0, stream>>>(expand_w + 256 * DDIM, (u32*)wexp8i);
  cast8_kernel<<<2048, 256, 0, stream>>>(project_w, (u32*)wproj8, 524288, 256.0f);
  // q/k columns: M=8192, N=256, K=1024 (bf16)
  gemm_bt<<<dim3(64, 2), 256, 0, stream>>>(xn, wqk, h, HQK, DDIM, 0);
  // expand + fused GEGLU: 64 m x 16 n = 1024 blocks
  gemm1glu<<<1024, 512, 0, stream>>>((const char*)xn8, wexp8i, fused8, vbuf8);
  vT8_kernel<<<512, 256, 0, stream>>>(vbuf8, vTb);
  attn_mfma<<<256, 256, 0, stream>>>(h, vTb, fused8, pbm);
  // project: M=8192 (64 tiles) x N=1024 (8 tiles) = 512 blocks, BK=128
  gemmproj<<<512, 512, 0, stream>>>(fused8, wproj8, out, x, 1.0f / 256.0f);
}

// Round 12
// 149.930 us; speedup vs baseline: 1.0172x; 1.0172x over previous
//
#include <hip/hip_runtime.h>
#include <hip/hip_bf16.h>
#include <hip/hip_fp8.h>

typedef __bf16 bf16x8 __attribute__((ext_vector_type(8)));
typedef __bf16 bf16x4 __attribute__((ext_vector_type(4)));
typedef float f32x4 __attribute__((ext_vector_type(4)));
typedef unsigned int u32;
typedef __attribute__((address_space(3))) u32 lds_u32_t;
typedef __attribute__((address_space(1))) u32 glb_u32_t;

#define MROWS 8192      // B*S
#define DDIM 1024
#define EDIM 2048
#define HQK 256         // h buffer holds only q|k columns

#define S_BAR() asm volatile("s_barrier" ::: "memory")
#define S_VM0() asm volatile("s_waitcnt vmcnt(0)" ::: "memory")
#define SCHED_PIN() __builtin_amdgcn_sched_barrier(0)

__device__ __forceinline__ void async16(const void* g, void* l) {
  __builtin_amdgcn_global_load_lds((const glb_u32_t*)g, (lds_u32_t*)l, 16, 0, 0);
}

__device__ __forceinline__ u32 pack4_e4m3(float f0, float f1, float f2, float f3) {
  __hip_fp8_e4m3 a(f0), b(f1), c(f2), d(f3);
  return (u32)a.__x | ((u32)b.__x << 8) | ((u32)c.__x << 16) | ((u32)d.__x << 24);
}

// ---------------- LayerNorm + bf16 cast + fp8 cast ----------------
__global__ __launch_bounds__(256) void ln_kernel(const float* __restrict__ x,
                                                 const float* __restrict__ wgt,
                                                 __bf16* __restrict__ xn,
                                                 u32* __restrict__ xn8) {
  const int row = blockIdx.x;
  const int t = threadIdx.x;
  const float4 v = ((const float4*)(x + (size_t)row * DDIM))[t];
  float s = v.x + v.y + v.z + v.w;
  float ss = v.x * v.x + v.y * v.y + v.z * v.z + v.w * v.w;
  #pragma unroll
  for (int o = 32; o > 0; o >>= 1) {
    s += __shfl_down(s, o);
    ss += __shfl_down(ss, o);
  }
  __shared__ float red[8];
  const int lane = t & 63, wv = t >> 6;
  if (lane == 0) { red[wv] = s; red[4 + wv] = ss; }
  __syncthreads();
  s = red[0] + red[1] + red[2] + red[3];
  ss = red[4] + red[5] + red[6] + red[7];
  const float mu = s * (1.0f / 1024.0f);
  const float rstd = rsqrtf(ss * (1.0f / 1024.0f) - mu * mu + 1e-5f);
  const float4 w4 = ((const float4*)wgt)[t];
  const float f0 = (v.x - mu) * rstd * w4.x;
  const float f1 = (v.y - mu) * rstd * w4.y;
  const float f2 = (v.z - mu) * rstd * w4.z;
  const float f3 = (v.w - mu) * rstd * w4.w;
  bf16x4 o;
  o[0] = (__bf16)f0; o[1] = (__bf16)f1; o[2] = (__bf16)f2; o[3] = (__bf16)f3;
  ((bf16x4*)(xn + (size_t)row * DDIM))[t] = o;
  xn8[row * 256 + t] = pack4_e4m3(f0, f1, f2, f3);
}

// ---------------- fp32 -> bf16 weight cast ----------------
__global__ __launch_bounds__(256) void cast_kernel(const float* __restrict__ src,
                                                   __bf16* __restrict__ dst, int n4) {
  const int i = blockIdx.x * 256 + threadIdx.x;
  if (i < n4) {
    const float4 v = ((const float4*)src)[i];
    bf16x4 o;
    o[0] = (__bf16)v.x; o[1] = (__bf16)v.y; o[2] = (__bf16)v.z; o[3] = (__bf16)v.w;
    ((bf16x4*)dst)[i] = o;
  }
}

// ---------------- fp32 -> fp8 weight cast (pre-scaled) ----------------
__global__ __launch_bounds__(256) void cast8_kernel(const float* __restrict__ src,
                                                    u32* __restrict__ dst, int n4, float scale) {
  const int i = blockIdx.x * 256 + threadIdx.x;
  if (i < n4) {
    const float4 v = ((const float4*)src)[i];
    dst[i] = pack4_e4m3(v.x * scale, v.y * scale, v.z * scale, v.w * scale);
  }
}

// ------ fp32 -> fp8 interleaved expand-weight cast (lin/pre frag pairs) ------
__global__ __launch_bounds__(256) void cast8i_kernel(const float* __restrict__ src,
                                                     u32* __restrict__ dst) {
  const int i = blockIdx.x * 256 + threadIdx.x;   // 4096*256
  const int rp = i >> 8, k4 = i & 255;
  const int c = ((rp >> 5) << 4) | (rp & 15);
  const int pre = (rp >> 4) & 1;
  const float4 v = *(const float4*)(src + ((size_t)(pre * 2048 + c)) * 1024 + k4 * 4);
  dst[i] = pack4_e4m3(v.x * 16.0f, v.y * 16.0f, v.z * 16.0f, v.w * 16.0f);
}

// ------------- small m97-style bf16 GEMM (skinny q/k columns) -------------
__global__ __launch_bounds__(256) void gemm_bt(const __bf16* __restrict__ A,
                                               const __bf16* __restrict__ Bt,
                                               __bf16* __restrict__ Cout,
                                               int Ndim, int Kdim, int coff) {
  __shared__ __bf16 As[128 * 32];
  __shared__ __bf16 Bs[128 * 32];
  const int t = threadIdx.x;
  const int lane = t & 63;
  const int w = t >> 6;
  const int wm = w >> 1, wn = w & 1;
  const int m0 = blockIdx.x * 128;
  const int n0 = blockIdx.y * 128;

  f32x4 acc[4][4] = {};

  const int cA = w * 2;
  const int sr = cA * 16 + (lane >> 2);
  const int sc = (lane & 3) * 8;
  const __bf16* gA0 = A + (size_t)(m0 + sr) * Kdim + sc;
  const __bf16* gA1 = A + (size_t)(m0 + sr + 16) * Kdim + sc;
  const __bf16* gB0 = Bt + (size_t)(n0 + sr) * Kdim + sc;
  const __bf16* gB1 = Bt + (size_t)(n0 + sr + 16) * Kdim + sc;
  __bf16* lA0 = As + cA * 512;
  __bf16* lA1 = As + (cA + 1) * 512;
  __bf16* lB0 = Bs + cA * 512;
  __bf16* lB1 = Bs + (cA + 1) * 512;

  const int lr = lane & 15;
  const int lk = (lane >> 4) * 8;
  const int nk = Kdim >> 5;

  for (int kt = 0; kt < nk; ++kt) {
    __syncthreads();
    const int ko = kt * 32;
    async16(gA0 + ko, lA0);
    async16(gA1 + ko, lA1);
    async16(gB0 + ko, lB0);
    async16(gB1 + ko, lB1);
    __syncthreads();
    bf16x8 a[4], b[4];
    #pragma unroll
    for (int i = 0; i < 4; ++i)
      a[i] = *(const bf16x8*)&As[(wm * 64 + i * 16 + lr) * 32 + lk];
    #pragma unroll
    for (int i = 0; i < 4; ++i)
      b[i] = *(const bf16x8*)&Bs[(wn * 64 + i * 16 + lr) * 32 + lk];
    #pragma unroll
    for (int i = 0; i < 4; ++i)
      #pragma unroll
      for (int j = 0; j < 4; ++j)
        acc[i][j] = __builtin_amdgcn_mfma_f32_16x16x32_bf16(a[i], b[j], acc[i][j], 0, 0, 0);
  }

  #pragma unroll
  for (int i = 0; i < 4; ++i) {
    const int rbase = m0 + wm * 64 + i * 16 + ((lane >> 4) << 2);
    #pragma unroll
    for (int j = 0; j < 4; ++j) {
      const int col = coff + n0 + wn * 64 + j * 16 + (lane & 15);
      #pragma unroll
      for (int r = 0; r < 4; ++r)
        Cout[(size_t)(rbase + r) * Ndim + col] = (__bf16)acc[i][j][r];
    }
  }
}

// ------- fp8 GEMM + fused GEGLU epilogue, TRANSPOSED output -------
// 256 threads, 4 waves (2Mx2N), wave tile 64x128. BM=128, BN=256
// (interleaved lin/pre 16-col frags), BK=64. mfma(A=weight frag, B=xn frag)
// -> C^T: reg r = 4 consecutive output cols -> geglu fp32 -> one u32 store.
__global__ __launch_bounds__(256, 2) void gemm1glu(const char* __restrict__ A8,
                                                   const char* __restrict__ B8,
                                                   char* __restrict__ fused8,
                                                   char* __restrict__ vbuf8) {
  constexpr int ASZ = 128 * 64;
  constexpr int BSZ = 256 * 64;
  constexpr int Kdim = 1024;
  __shared__ alignas(16) char As[2 * ASZ];
  __shared__ alignas(16) char Bs[2 * BSZ];

  const int tid = threadIdx.x;
  const int lane = tid & 63;
  const int w = tid >> 6;
  const int wm = w >> 1, wn = w & 1;

  const int qq = gridDim.x >> 3;
  const int wgid = (blockIdx.x & 7) * qq + (blockIdx.x >> 3);
  const int m0 = (wgid / 16) * 128;
  const int nblk = wgid % 16;
  const int n0r = nblk * 256;          // weight-row base

  f32x4 acc[8][4] = {};                // acc[nf][mf] (transposed)

  // staging: 256 threads; thread covers units tid + c*256
  const int rowS = tid >> 2;           // 0..63 (+64 per chunk for A, +64 per chunk for B)
  const int uS = tid & 3;
  const int luS = uS ^ ((rowS >> 1) & 3);   // (row>>1)&3 invariant under +64
  const char* gA = A8 + (size_t)(m0 + rowS) * Kdim + luS * 16;
  const char* gB = B8 + (size_t)(n0r + rowS) * Kdim + luS * 16;
  char* lA = (char*)As;
  char* lB = (char*)Bs;

  const int lr = lane & 15;
  const int hi = lane >> 4;
  const int sw = (lr >> 1) & 3;
  const int kof0 = ((((hi >> 1)) ^ sw) << 4) + (hi & 1) * 8;
  const int kof1 = (((2 + (hi >> 1)) ^ sw) << 4) + (hi & 1) * 8;
  const int rowA = (wm * 64 + lr) * 64;
  const int rowB = (wn * 128 + lr) * 64;
  const int NT = Kdim >> 6;

  // prologue: stage tile 0 into buf 0 (A: 2 chunks, B: 4 chunks)
  #pragma unroll
  for (int c = 0; c < 2; ++c) async16(gA + (size_t)c * 64 * Kdim, lA + c * 4096 + tid * 16);
  #pragma unroll
  for (int c = 0; c < 4; ++c) async16(gB + (size_t)c * 64 * Kdim, lB + c * 4096 + tid * 16);
  S_VM0();
  S_BAR();

  for (int t = 0; t < NT; ++t) {
    const int buf = t & 1;
    const char* pA = lA + buf * ASZ + rowA;
    const char* pB = lB + buf * BSZ + rowB;

    long a0[4], b0[8], a1[4], b1[8];
    #pragma unroll
    for (int ni = 0; ni < 8; ++ni) b0[ni] = *(const long*)(pB + ni * 1024 + kof0);
    #pragma unroll
    for (int mi = 0; mi < 4; ++mi) a0[mi] = *(const long*)(pA + mi * 1024 + kof0);
    SCHED_PIN();
    #pragma unroll
    for (int ni = 0; ni < 8; ++ni) b1[ni] = *(const long*)(pB + ni * 1024 + kof1);
    #pragma unroll
    for (int mi = 0; mi < 4; ++mi) a1[mi] = *(const long*)(pA + mi * 1024 + kof1);
    SCHED_PIN();
    if (t + 1 < NT) {
      const char* gAt = gA + (size_t)(t + 1) * 64;
      const char* gBt = gB + (size_t)(t + 1) * 64;
      char* lAd = lA + (buf ^ 1) * ASZ + tid * 16;
      char* lBd = lB + (buf ^ 1) * BSZ + tid * 16;
      #pragma unroll
      for (int c = 0; c < 2; ++c) async16(gAt + (size_t)c * 64 * Kdim, lAd + c * 4096);
      #pragma unroll
      for (int c = 0; c < 4; ++c) async16(gBt + (size_t)c * 64 * Kdim, lBd + c * 4096);
    }
    SCHED_PIN();
    __builtin_amdgcn_s_setprio(1);
    #pragma unroll
    for (int ni = 0; ni < 8; ++ni)
      #pragma unroll
      for (int mi = 0; mi < 4; ++mi)
        acc[ni][mi] = __builtin_amdgcn_mfma_f32_16x16x32_fp8_fp8(b0[ni], a0[mi], acc[ni][mi], 0, 0, 0);
    __builtin_amdgcn_s_setprio(0);
    SCHED_PIN();
    __builtin_amdgcn_s_setprio(1);
    #pragma unroll
    for (int ni = 0; ni < 8; ++ni)
      #pragma unroll
      for (int mi = 0; mi < 4; ++mi)
        acc[ni][mi] = __builtin_amdgcn_mfma_f32_16x16x32_fp8_fp8(b1[ni], a1[mi], acc[ni][mi], 0, 0, 0);
    __builtin_amdgcn_s_setprio(0);
    SCHED_PIN();
    if (t + 1 < NT) S_VM0();
    S_BAR();
  }

  // fused GEGLU epilogue (transposed): pair p uses frags (2p, 2p+1);
  // output col cb = (nblk*8 + wn*4 + p)*16 + hi*4 ; m = m0+wm*64+mf*16+(lane&15)
  const bool isv = nblk >= 8;
  #pragma unroll
  for (int p = 0; p < 4; ++p) {
    const int cb = (nblk * 8 + wn * 4 + p) * 16 + hi * 4;
    #pragma unroll
    for (int mf = 0; mf < 4; ++mf) {
      const int m = m0 + wm * 64 + mf * 16 + (lane & 15);
      float g[4];
      #pragma unroll
      for (int r = 0; r < 4; ++r) {
        const float l = acc[2 * p][mf][r] * 0.0625f;
        const float q = acc[2 * p + 1][mf][r] * 0.0625f;
        g[r] = l * 0.5f * q * (1.0f + erff(q * 0.70710678118f));
      }
      const u32 pk = pack4_e4m3(g[0], g[1], g[2], g[3]);
      if (isv) *(u32*)&vbuf8[(size_t)m * 1024 + (cb - 1024)] = pk;
      else     *(u32*)&fused8[(size_t)m * EDIM + cb] = pk;
    }
  }
}

// ---------------- fp8 project GEMM, 256 threads, BM=128 BN=128 BK=128 --------
// 4 waves (2Mx2N), wave tile 64x64, 8-unit XOR swizzle, 64KB LDS -> 2 blk/CU.
__global__ __launch_bounds__(256, 2) void gemmproj(const char* __restrict__ A8,
                                                   const char* __restrict__ B8,
                                                   float* __restrict__ out,
                                                   const float* __restrict__ resid,
                                                   float scl) {
  constexpr int ASZ = 128 * 128;   // 16KB
  constexpr int BSZ = 128 * 128;   // 16KB
  constexpr int Kdim = 2048;
  __shared__ alignas(16) char As[2 * ASZ];
  __shared__ alignas(16) char Bs[2 * BSZ];

  const int tid = threadIdx.x;
  const int lane = tid & 63;
  const int w = tid >> 6;
  const int wm = w >> 1, wn = w & 1;

  const int qq = gridDim.x >> 3;
  const int wgid = (blockIdx.x & 7) * qq + (blockIdx.x >> 3);
  const int m0 = (wgid / 8) * 128;
  const int n0 = (wgid % 8) * 128;

  f32x4 acc[4][4] = {};

  const int rowS = tid >> 3;           // 0..31 (+32 per chunk)
  const int uS = tid & 7;
  const int luS = uS ^ (rowS & 7);     // (row&7) invariant under +32
  const char* gA = A8 + (size_t)(m0 + rowS) * Kdim + luS * 16;
  const char* gB = B8 + (size_t)(n0 + rowS) * Kdim + luS * 16;
  char* lA = (char*)As;
  char* lB = (char*)Bs;

  const int lr = lane & 15;
  const int hi = lane >> 4;
  int kof[4];
  #pragma unroll
  for (int kq = 0; kq < 4; ++kq)
    kof[kq] = (((kq * 2 + (hi >> 1)) ^ (lr & 7)) << 4) + (hi & 1) * 8;
  const int rowA = (wm * 64 + lr) * 128;
  const int rowB = (wn * 64 + lr) * 128;
  const int NT = Kdim >> 7;            // 16

  // prologue: stage tile 0 (A: 4 chunks of 32 rows, B: 4 chunks)
  #pragma unroll
  for (int c = 0; c < 4; ++c) {
    async16(gA + (size_t)c * 32 * Kdim, lA + c * 4096 + tid * 16);
    async16(gB + (size_t)c * 32 * Kdim, lB + c * 4096 + tid * 16);
  }
  S_VM0();
  S_BAR();

  for (int t = 0; t < NT; ++t) {
    const int buf = t & 1;
    const char* pA = lA + buf * ASZ + rowA;
    const char* pB = lB + buf * BSZ + rowB;

    long a[4][4], bb[4][4];
    #pragma unroll
    for (int kq = 0; kq < 4; ++kq) {
      #pragma unroll
      for (int ni = 0; ni < 4; ++ni) bb[kq][ni] = *(const long*)(pB + ni * 2048 + kof[kq]);
      #pragma unroll
      for (int mi = 0; mi < 4; ++mi) a[kq][mi] = *(const long*)(pA + mi * 2048 + kof[kq]);
    }
    SCHED_PIN();
    if (t + 1 < NT) {
      const char* gAt = gA + (size_t)(t + 1) * 128;
      const char* gBt = gB + (size_t)(t + 1) * 128;
      char* lAd = lA + (buf ^ 1) * ASZ + tid * 16;
      char* lBd = lB + (buf ^ 1) * BSZ + tid * 16;
      #pragma unroll
      for (int c = 0; c < 4; ++c) {
        async16(gAt + (size_t)c * 32 * Kdim, lAd + c * 4096);
        async16(gBt + (size_t)c * 32 * Kdim, lBd + c * 4096);
      }
    }
    SCHED_PIN();
    #pragma unroll
    for (int kq = 0; kq < 4; ++kq) {
      __builtin_amdgcn_s_setprio(1);
      #pragma unroll
      for (int mi = 0; mi < 4; ++mi)
        #pragma unroll
        for (int ni = 0; ni < 4; ++ni)
          acc[mi][ni] = __builtin_amdgcn_mfma_f32_16x16x32_fp8_fp8(a[kq][mi], bb[kq][ni], acc[mi][ni], 0, 0, 0);
      __builtin_amdgcn_s_setprio(0);
      SCHED_PIN();
    }
    if (t + 1 < NT) S_VM0();
    S_BAR();
  }

  #pragma unroll
  for (int mi = 0; mi < 4; ++mi) {
    const int rbase = m0 + wm * 64 + mi * 16 + (hi << 2);
    #pragma unroll
    for (int ni = 0; ni < 4; ++ni) {
      const int col = n0 + wn * 64 + ni * 16 + (lane & 15);
      #pragma unroll
      for (int r = 0; r < 4; ++r) {
        const size_t off = (size_t)(rbase + r) * DDIM + col;
        out[off] = resid[off] + acc[mi][ni][r] * scl;
      }
    }
  }
}

// --------- fp8 V transpose: vbuf8[8192][1024] -> vTb[b][h][sblk16][d256][s64] ------
__global__ __launch_bounds__(256) void vT8_kernel(const char* __restrict__ vbuf8,
                                                  char* __restrict__ vTb) {
  const int blk = blockIdx.x;          // 512
  const int sblk = blk & 15;
  const int head = (blk >> 4) & 3;
  const int b = blk >> 6;
  const int t = threadIdx.x;
  __shared__ u32 vt[64][66];

  const int s_l = t >> 2, q4 = t & 3;
  const uint4* src = (const uint4*)&vbuf8[(size_t)(b * 1024 + sblk * 64 + s_l) * 1024 +
                                          head * 256 + q4 * 64];
  #pragma unroll
  for (int c = 0; c < 4; ++c) {
    const uint4 ww = src[c];
    vt[s_l][q4 * 16 + c * 4 + 0] = ww.x;
    vt[s_l][q4 * 16 + c * 4 + 1] = ww.y;
    vt[s_l][q4 * 16 + c * 4 + 2] = ww.z;
    vt[s_l][q4 * 16 + c * 4 + 3] = ww.w;
  }
  __syncthreads();
  const int d = t;
  const int wsel = (d & 3) * 8;
  char* dst = vTb + (((size_t)(b * 4 + head) * 16 + sblk) * 256 + d) * 64;
  #pragma unroll
  for (int c = 0; c < 4; ++c) {
    u32 wo[4];
    #pragma unroll
    for (int k = 0; k < 4; ++k) {
      const int s0 = c * 16 + k * 4;
      const u32 r0 = vt[s0 + 0][d >> 2];
      const u32 r1 = vt[s0 + 1][d >> 2];
      const u32 r2 = vt[s0 + 2][d >> 2];
      const u32 r3 = vt[s0 + 3][d >> 2];
      wo[k] = ((r0 >> wsel) & 0xffu) | (((r1 >> wsel) & 0xffu) << 8) |
              (((r2 >> wsel) & 0xffu) << 16) | (((r3 >> wsel) & 0xffu) << 24);
    }
    *(uint4*)(dst + c * 16) = make_uint4(wo[0], wo[1], wo[2], wo[3]);
  }
}

// ------------- MFMA sliding-window attention (W=32) -------------
__global__ __launch_bounds__(256, 2) void attn_mfma(const __bf16* __restrict__ h,
                                                    const char* __restrict__ vTb,
                                                    char* __restrict__ fused8,
                                                    const float* __restrict__ pbm) {
  const int blk = blockIdx.x;          // 256
  const int qblk = blk & 7;
  const int head = (blk >> 3) & 3;
  const int b = blk >> 5;
  const int tid = threadIdx.x;
  const int lane = tid & 63;
  const int w = tid >> 6;
  __shared__ char vt[256 * 176];
  __shared__ char pl[4][32 * 80];

  const float p = pbm[0];
  const float sp = (p > 20.0f) ? p : log1pf(expf(p));

  {
    const int m = qblk * 2;
    const char* base = vTb + ((size_t)(b * 4 + head) * 16) * 16384;
    #pragma unroll
    for (int it = 0; it < 11; ++it) {
      const int U = it * 256 + tid;
      const int d = U / 11;
      const int slot = U - d * 11;
      int sb, so;
      if (slot >= 10)      { sb = m; so = 0; }
      else if (slot < 2)   { sb = m - 1; so = 32 + slot * 16; }
      else if (slot < 6)   { sb = m; so = (slot - 2) * 16; }
      else                 { sb = m + 1; so = (slot - 6) * 16; }
      if (sb < 0) sb = 0;
      async16(base + ((size_t)sb * 256 + d) * 64 + so, vt + U * 16);
    }
  }

  const int col = lane & 15;
  const int hi = lane >> 4;
  const int qb = qblk * 128 + w * 32;
  const int kb = qb - 32;

  f32x4 sc[4][2] = {};
  bf16x8 afr[4], bfr[2];
  #pragma unroll
  for (int mf = 0; mf < 4; ++mf) {
    int key = kb + mf * 16 + col;
    if (key < 0) key = 0;
    afr[mf] = *(const bf16x8*)&h[(size_t)(b * 1024 + key) * HQK + 128 + head * 32 + hi * 8];
  }
  #pragma unroll
  for (int nf = 0; nf < 2; ++nf)
    bfr[nf] = *(const bf16x8*)&h[(size_t)(b * 1024 + qb + nf * 16 + col) * HQK + head * 32 + hi * 8];
  #pragma unroll
  for (int mf = 0; mf < 4; ++mf)
    #pragma unroll
    for (int nf = 0; nf < 2; ++nf)
      sc[mf][nf] = __builtin_amdgcn_mfma_f32_16x16x32_bf16(afr[mf], bfr[nf], sc[mf][nf], 0, 0, 0);

  #pragma unroll
  for (int nf = 0; nf < 2; ++nf) {
    #pragma unroll
    for (int mf = 0; mf < 4; ++mf)
      #pragma unroll
      for (int r = 0; r < 4; ++r) {
        const int delta = mf * 16 + hi * 4 + r - nf * 16 - col - 32;
        const int keyabs = kb + mf * 16 + hi * 4 + r;
        const bool valid = (delta <= 0) & (delta >= -31) & (keyabs >= 0);
        sc[mf][nf][r] = valid ? sc[mf][nf][r] * 0.1767766953f + sp * (float)delta : -1e30f;
      }
    float m = -1e30f;
    #pragma unroll
    for (int mf = 0; mf < 4; ++mf)
      #pragma unroll
      for (int r = 0; r < 4; ++r) m = fmaxf(m, sc[mf][nf][r]);
    m = fmaxf(m, __shfl_xor(m, 16));
    m = fmaxf(m, __shfl_xor(m, 32));
    float s = 0.0f;
    #pragma unroll
    for (int mf = 0; mf < 4; ++mf)
      #pragma unroll
      for (int r = 0; r < 4; ++r) {
        const float e = __expf(sc[mf][nf][r] - m);
        sc[mf][nf][r] = e;
        s += e;
      }
    s += __shfl_xor(s, 16);
    s += __shfl_xor(s, 32);
    const float inv = 1.0f / s;
    #pragma unroll
    for (int mf = 0; mf < 4; ++mf) {
      const u32 pk = pack4_e4m3(sc[mf][nf][0] * inv, sc[mf][nf][1] * inv,
                                sc[mf][nf][2] * inv, sc[mf][nf][3] * inv);
      *(u32*)&pl[w][(nf * 16 + col) * 80 + mf * 16 + hi * 4] = pk;
    }
  }

  __syncthreads();

  const char* ppl = pl[w];
  const int kloc = w * 32;
  f32x4 ao[16][2] = {};
  #pragma unroll
  for (int kf = 0; kf < 2; ++kf) {
    long bfrag[2];
    #pragma unroll
    for (int nf = 0; nf < 2; ++nf)
      bfrag[nf] = *(const long*)&ppl[(nf * 16 + col) * 80 + kf * 32 + hi * 8];
    #pragma unroll
    for (int mf = 0; mf < 16; ++mf) {
      const long af = *(const long*)&vt[(mf * 16 + col) * 176 + kloc + kf * 32 + hi * 8];
      #pragma unroll
      for (int nf = 0; nf < 2; ++nf)
        ao[mf][nf] = __builtin_amdgcn_mfma_f32_16x16x32_fp8_fp8(af, bfrag[nf], ao[mf][nf], 0, 0, 0);
    }
  }

  #pragma unroll
  for (int mf = 0; mf < 16; ++mf)
    #pragma unroll
    for (int nf = 0; nf < 2; ++nf) {
      const u32 pk = pack4_e4m3(ao[mf][nf][0], ao[mf][nf][1], ao[mf][nf][2], ao[mf][nf][3]);
      *(u32*)&fused8[(size_t)(b * 1024 + qb + nf * 16 + col) * EDIM + 1024 +
                     head * 256 + mf * 16 + hi * 4] = pk;
    }
}

// ---------------- host launch ----------------
extern "C" void kernel_launch(void* const* d_in, const int* in_sizes, int n_in,
                              void* d_out, int out_size, void* d_ws, size_t ws_size,
                              hipStream_t stream) {
  const float* x = (const float*)d_in[0];
  const float* norm_w = (const float*)d_in[2];
  const float* expand_w = (const float*)d_in[3];
  const float* project_w = (const float*)d_in[4];
  const float* pbm = (const float*)d_in[5];
  float* out = (float*)d_out;

  char* ws = (char*)d_ws;
  __bf16* xn    = (__bf16*)(ws);                  // 16,777,216
  u32*    xn8   = (u32*)(ws + 16777216);          //  8,388,608
  __bf16* wqk   = (__bf16*)(ws + 25165824);       //    524,288
  char*   wexp8i= (char*)(ws + 25690112);         //  4,194,304 (interleaved, x16)
  char*   wproj8= (char*)(ws + 29884416);         //  2,097,152 (x256)
  __bf16* h     = (__bf16*)(ws + 31981568);       //  4,194,304 (q|k only)
  char*   fused8= (char*)(ws + 36175872);         // 16,777,216
  char*   vbuf8 = (char*)(ws + 52953088);         //  8,388,608
  char*   vTb   = (char*)(ws + 61341696);         //  8,388,608

  ln_kernel<<<MROWS, 256, 0, stream>>>(x, norm_w, xn, xn8);
  cast_kernel<<<256, 256, 0, stream>>>(expand_w, wqk, 65536);
  cast8i_kernel<<<4096, 256, 0, stream>>>(expand_w + 256 * DDIM, (u32*)wexp8i);
  cast8_kernel<<<2048, 256, 0, stream>>>(project_w, (u32*)wproj8, 524288, 256.0f);
  // q/k columns: M=8192, N=256, K=1024 (bf16)
  gemm_bt<<<dim3(64, 2), 256, 0, stream>>>(xn, wqk, h, HQK, DDIM, 0);
  // expand + fused GEGLU: 64 m x 16 n = 1024 blocks, 256 threads
  gemm1glu<<<1024, 256, 0, stream>>>((const char*)xn8, wexp8i, fused8, vbuf8);
  vT8_kernel<<<512, 256, 0, stream>>>(vbuf8, vTb);
  attn_mfma<<<256, 256, 0, stream>>>(h, vTb, fused8, pbm);
  // project: M=8192 (64 tiles) x N=1024 (8 tiles) = 512 blocks, 256 threads
  gemmproj<<<512, 256, 0, stream>>>(fused8, wproj8, out, x, 1.0f / 256.0f);
}

// Round 13
// 145.009 us; speedup vs baseline: 1.0517x; 1.0339x over previous
//
#include <hip/hip_runtime.h>
#include <hip/hip_bf16.h>
#include <hip/hip_fp8.h>

typedef __bf16 bf16x8 __attribute__((ext_vector_type(8)));
typedef __bf16 bf16x4 __attribute__((ext_vector_type(4)));
typedef float f32x4 __attribute__((ext_vector_type(4)));
typedef unsigned int u32;
typedef __attribute__((address_space(3))) u32 lds_u32_t;
typedef __attribute__((address_space(1))) u32 glb_u32_t;

#define MROWS 8192      // B*S
#define DDIM 1024
#define EDIM 2048
#define HQK 256         // h buffer holds only q|k columns

#define S_BAR() asm volatile("s_barrier" ::: "memory")
#define S_VM0() asm volatile("s_waitcnt vmcnt(0)" ::: "memory")
#define SCHED_PIN() __builtin_amdgcn_sched_barrier(0)

__device__ __forceinline__ void async16(const void* g, void* l) {
  __builtin_amdgcn_global_load_lds((const glb_u32_t*)g, (lds_u32_t*)l, 16, 0, 0);
}

__device__ __forceinline__ u32 pack4_e4m3(float f0, float f1, float f2, float f3) {
  __hip_fp8_e4m3 a(f0), b(f1), c(f2), d(f3);
  return (u32)a.__x | ((u32)b.__x << 8) | ((u32)c.__x << 16) | ((u32)d.__x << 24);
}

// ---------------- LayerNorm + bf16 cast + fp8 cast ----------------
__global__ __launch_bounds__(256) void ln_kernel(const float* __restrict__ x,
                                                 const float* __restrict__ wgt,
                                                 __bf16* __restrict__ xn,
                                                 u32* __restrict__ xn8) {
  const int row = blockIdx.x;
  const int t = threadIdx.x;
  const float4 v = ((const float4*)(x + (size_t)row * DDIM))[t];
  float s = v.x + v.y + v.z + v.w;
  float ss = v.x * v.x + v.y * v.y + v.z * v.z + v.w * v.w;
  #pragma unroll
  for (int o = 32; o > 0; o >>= 1) {
    s += __shfl_down(s, o);
    ss += __shfl_down(ss, o);
  }
  __shared__ float red[8];
  const int lane = t & 63, wv = t >> 6;
  if (lane == 0) { red[wv] = s; red[4 + wv] = ss; }
  __syncthreads();
  s = red[0] + red[1] + red[2] + red[3];
  ss = red[4] + red[5] + red[6] + red[7];
  const float mu = s * (1.0f / 1024.0f);
  const float rstd = rsqrtf(ss * (1.0f / 1024.0f) - mu * mu + 1e-5f);
  const float4 w4 = ((const float4*)wgt)[t];
  const float f0 = (v.x - mu) * rstd * w4.x;
  const float f1 = (v.y - mu) * rstd * w4.y;
  const float f2 = (v.z - mu) * rstd * w4.z;
  const float f3 = (v.w - mu) * rstd * w4.w;
  bf16x4 o;
  o[0] = (__bf16)f0; o[1] = (__bf16)f1; o[2] = (__bf16)f2; o[3] = (__bf16)f3;
  ((bf16x4*)(xn + (size_t)row * DDIM))[t] = o;
  xn8[row * 256 + t] = pack4_e4m3(f0, f1, f2, f3);
}

// ---------------- fp32 -> bf16 weight cast ----------------
__global__ __launch_bounds__(256) void cast_kernel(const float* __restrict__ src,
                                                   __bf16* __restrict__ dst, int n4) {
  const int i = blockIdx.x * 256 + threadIdx.x;
  if (i < n4) {
    const float4 v = ((const float4*)src)[i];
    bf16x4 o;
    o[0] = (__bf16)v.x; o[1] = (__bf16)v.y; o[2] = (__bf16)v.z; o[3] = (__bf16)v.w;
    ((bf16x4*)dst)[i] = o;
  }
}

// ---------------- fp32 -> fp8 weight cast (pre-scaled) ----------------
__global__ __launch_bounds__(256) void cast8_kernel(const float* __restrict__ src,
                                                    u32* __restrict__ dst, int n4, float scale) {
  const int i = blockIdx.x * 256 + threadIdx.x;
  if (i < n4) {
    const float4 v = ((const float4*)src)[i];
    dst[i] = pack4_e4m3(v.x * scale, v.y * scale, v.z * scale, v.w * scale);
  }
}

// ------ fp32 -> fp8 interleaved expand-weight cast (lin/pre frag pairs) ------
__global__ __launch_bounds__(256) void cast8i_kernel(const float* __restrict__ src,
                                                     u32* __restrict__ dst) {
  const int i = blockIdx.x * 256 + threadIdx.x;   // 4096*256
  const int rp = i >> 8, k4 = i & 255;
  const int c = ((rp >> 5) << 4) | (rp & 15);
  const int pre = (rp >> 4) & 1;
  const float4 v = *(const float4*)(src + ((size_t)(pre * 2048 + c)) * 1024 + k4 * 4);
  dst[i] = pack4_e4m3(v.x * 16.0f, v.y * 16.0f, v.z * 16.0f, v.w * 16.0f);
}

// ------------- small m97-style bf16 GEMM (skinny q/k columns) -------------
__global__ __launch_bounds__(256) void gemm_bt(const __bf16* __restrict__ A,
                                               const __bf16* __restrict__ Bt,
                                               __bf16* __restrict__ Cout,
                                               int Ndim, int Kdim, int coff) {
  __shared__ __bf16 As[128 * 32];
  __shared__ __bf16 Bs[128 * 32];
  const int t = threadIdx.x;
  const int lane = t & 63;
  const int w = t >> 6;
  const int wm = w >> 1, wn = w & 1;
  const int m0 = blockIdx.x * 128;
  const int n0 = blockIdx.y * 128;

  f32x4 acc[4][4] = {};

  const int cA = w * 2;
  const int sr = cA * 16 + (lane >> 2);
  const int sc = (lane & 3) * 8;
  const __bf16* gA0 = A + (size_t)(m0 + sr) * Kdim + sc;
  const __bf16* gA1 = A + (size_t)(m0 + sr + 16) * Kdim + sc;
  const __bf16* gB0 = Bt + (size_t)(n0 + sr) * Kdim + sc;
  const __bf16* gB1 = Bt + (size_t)(n0 + sr + 16) * Kdim + sc;
  __bf16* lA0 = As + cA * 512;
  __bf16* lA1 = As + (cA + 1) * 512;
  __bf16* lB0 = Bs + cA * 512;
  __bf16* lB1 = Bs + (cA + 1) * 512;

  const int lr = lane & 15;
  const int lk = (lane >> 4) * 8;
  const int nk = Kdim >> 5;

  for (int kt = 0; kt < nk; ++kt) {
    __syncthreads();
    const int ko = kt * 32;
    async16(gA0 + ko, lA0);
    async16(gA1 + ko, lA1);
    async16(gB0 + ko, lB0);
    async16(gB1 + ko, lB1);
    __syncthreads();
    bf16x8 a[4], b[4];
    #pragma unroll
    for (int i = 0; i < 4; ++i)
      a[i] = *(const bf16x8*)&As[(wm * 64 + i * 16 + lr) * 32 + lk];
    #pragma unroll
    for (int i = 0; i < 4; ++i)
      b[i] = *(const bf16x8*)&Bs[(wn * 64 + i * 16 + lr) * 32 + lk];
    #pragma unroll
    for (int i = 0; i < 4; ++i)
      #pragma unroll
      for (int j = 0; j < 4; ++j)
        acc[i][j] = __builtin_amdgcn_mfma_f32_16x16x32_bf16(a[i], b[j], acc[i][j], 0, 0, 0);
  }

  #pragma unroll
  for (int i = 0; i < 4; ++i) {
    const int rbase = m0 + wm * 64 + i * 16 + ((lane >> 4) << 2);
    #pragma unroll
    for (int j = 0; j < 4; ++j) {
      const int col = coff + n0 + wn * 64 + j * 16 + (lane & 15);
      #pragma unroll
      for (int r = 0; r < 4; ++r)
        Cout[(size_t)(rbase + r) * Ndim + col] = (__bf16)acc[i][j][r];
    }
  }
}

// ------- fp8 GEMM + fused GEGLU epilogue, proj-style structure -------
// 256 threads, 4 waves (2Mx2N), wave tile 64x64, BM=128, BN=128 weight-rows,
// BK=128 (128B rows, 8-unit XOR swizzle -> conflict-free), 64KB LDS -> 2 blk/CU.
// mfma(A=w_frag, B=xn_frag) -> C^T: reg r = 4 consecutive output cols.
// Weight layout (cast8i): 32-row groups = 16 lin rows + 16 pre rows.
__global__ __launch_bounds__(256, 2) void gemm1glu(const char* __restrict__ A8,
                                                   const char* __restrict__ B8,
                                                   char* __restrict__ fused8,
                                                   char* __restrict__ vbuf8) {
  constexpr int ASZ = 128 * 128;   // 16KB
  constexpr int BSZ = 128 * 128;   // 16KB
  constexpr int Kdim = 1024;
  __shared__ alignas(16) char As[2 * ASZ];
  __shared__ alignas(16) char Bs[2 * BSZ];

  const int tid = threadIdx.x;
  const int lane = tid & 63;
  const int w = tid >> 6;
  const int wm = w >> 1, wn = w & 1;

  const int qq = gridDim.x >> 3;
  const int wgid = (blockIdx.x & 7) * qq + (blockIdx.x >> 3);
  const int m0 = (wgid / 32) * 128;
  const int nblk = wgid % 32;
  const int n0r = nblk * 128;          // weight-row base

  f32x4 acc[4][4] = {};                // acc[nf][mf] (transposed)

  const int rowS = tid >> 3;           // 0..31 (+32 per chunk)
  const int uS = tid & 7;
  const int luS = uS ^ (rowS & 7);     // (row&7) invariant under +32
  const char* gA = A8 + (size_t)(m0 + rowS) * Kdim + luS * 16;
  const char* gB = B8 + (size_t)(n0r + rowS) * Kdim + luS * 16;
  char* lA = (char*)As;
  char* lB = (char*)Bs;

  const int lr = lane & 15;
  const int hi = lane >> 4;
  int kof[4];
  #pragma unroll
  for (int kq = 0; kq < 4; ++kq)
    kof[kq] = (((kq * 2 + (hi >> 1)) ^ (lr & 7)) << 4) + (hi & 1) * 8;
  const int rowA = (wm * 64 + lr) * 128;
  const int rowB = (wn * 64 + lr) * 128;
  const int NT = Kdim >> 7;            // 8

  // prologue: stage tile 0 (A: 4 chunks of 32 rows, B: 4 chunks)
  #pragma unroll
  for (int c = 0; c < 4; ++c) {
    async16(gA + (size_t)c * 32 * Kdim, lA + c * 4096 + tid * 16);
    async16(gB + (size_t)c * 32 * Kdim, lB + c * 4096 + tid * 16);
  }
  S_VM0();
  S_BAR();

  for (int t = 0; t < NT; ++t) {
    const int buf = t & 1;
    const char* pA = lA + buf * ASZ + rowA;
    const char* pB = lB + buf * BSZ + rowB;

    long a[4][4], bb[4][4];
    #pragma unroll
    for (int kq = 0; kq < 4; ++kq) {
      #pragma unroll
      for (int ni = 0; ni < 4; ++ni) bb[kq][ni] = *(const long*)(pB + ni * 2048 + kof[kq]);
      #pragma unroll
      for (int mi = 0; mi < 4; ++mi) a[kq][mi] = *(const long*)(pA + mi * 2048 + kof[kq]);
    }
    SCHED_PIN();
    if (t + 1 < NT) {
      const char* gAt = gA + (size_t)(t + 1) * 128;
      const char* gBt = gB + (size_t)(t + 1) * 128;
      char* lAd = lA + (buf ^ 1) * ASZ + tid * 16;
      char* lBd = lB + (buf ^ 1) * BSZ + tid * 16;
      #pragma unroll
      for (int c = 0; c < 4; ++c) {
        async16(gAt + (size_t)c * 32 * Kdim, lAd + c * 4096);
        async16(gBt + (size_t)c * 32 * Kdim, lBd + c * 4096);
      }
    }
    SCHED_PIN();
    #pragma unroll
    for (int kq = 0; kq < 4; ++kq) {
      __builtin_amdgcn_s_setprio(1);
      #pragma unroll
      for (int ni = 0; ni < 4; ++ni)
        #pragma unroll
        for (int mi = 0; mi < 4; ++mi)
          acc[ni][mi] = __builtin_amdgcn_mfma_f32_16x16x32_fp8_fp8(bb[kq][ni], a[kq][mi], acc[ni][mi], 0, 0, 0);
      __builtin_amdgcn_s_setprio(0);
      SCHED_PIN();
    }
    if (t + 1 < NT) S_VM0();
    S_BAR();
  }

  // fused GEGLU epilogue (transposed): frag nf covers weight rows
  // n0r + wn*64 + nf*16 + hi*4 + r. Pair p = nf>>1 -> group g = nblk*4+wn*2+p,
  // lin = acc[2p], pre = acc[2p+1]; output col c = g*16 + hi*4 + r (consecutive).
  #pragma unroll
  for (int p = 0; p < 2; ++p) {
    const int g = nblk * 4 + wn * 2 + p;
    const int cb = g * 16 + hi * 4;
    const bool isv = g >= 64;
    #pragma unroll
    for (int mf = 0; mf < 4; ++mf) {
      const int m = m0 + wm * 64 + mf * 16 + (lane & 15);
      float gg[4];
      #pragma unroll
      for (int r = 0; r < 4; ++r) {
        const float l = acc[2 * p][mf][r] * 0.0625f;
        const float q = acc[2 * p + 1][mf][r] * 0.0625f;
        gg[r] = l * 0.5f * q * (1.0f + erff(q * 0.70710678118f));
      }
      const u32 pk = pack4_e4m3(gg[0], gg[1], gg[2], gg[3]);
      if (isv) *(u32*)&vbuf8[(size_t)m * 1024 + (cb - 1024)] = pk;
      else     *(u32*)&fused8[(size_t)m * EDIM + cb] = pk;
    }
  }
}

// ---------------- fp8 project GEMM, 256 threads, BM=128 BN=128 BK=128 --------
// 4 waves (2Mx2N), wave tile 64x64, 8-unit XOR swizzle, 64KB LDS -> 2 blk/CU.
__global__ __launch_bounds__(256, 2) void gemmproj(const char* __restrict__ A8,
                                                   const char* __restrict__ B8,
                                                   float* __restrict__ out,
                                                   const float* __restrict__ resid,
                                                   float scl) {
  constexpr int ASZ = 128 * 128;   // 16KB
  constexpr int BSZ = 128 * 128;   // 16KB
  constexpr int Kdim = 2048;
  __shared__ alignas(16) char As[2 * ASZ];
  __shared__ alignas(16) char Bs[2 * BSZ];

  const int tid = threadIdx.x;
  const int lane = tid & 63;
  const int w = tid >> 6;
  const int wm = w >> 1, wn = w & 1;

  const int qq = gridDim.x >> 3;
  const int wgid = (blockIdx.x & 7) * qq + (blockIdx.x >> 3);
  const int m0 = (wgid / 8) * 128;
  const int n0 = (wgid % 8) * 128;

  f32x4 acc[4][4] = {};

  const int rowS = tid >> 3;           // 0..31 (+32 per chunk)
  const int uS = tid & 7;
  const int luS = uS ^ (rowS & 7);     // (row&7) invariant under +32
  const char* gA = A8 + (size_t)(m0 + rowS) * Kdim + luS * 16;
  const char* gB = B8 + (size_t)(n0 + rowS) * Kdim + luS * 16;
  char* lA = (char*)As;
  char* lB = (char*)Bs;

  const int lr = lane & 15;
  const int hi = lane >> 4;
  int kof[4];
  #pragma unroll
  for (int kq = 0; kq < 4; ++kq)
    kof[kq] = (((kq * 2 + (hi >> 1)) ^ (lr & 7)) << 4) + (hi & 1) * 8;
  const int rowA = (wm * 64 + lr) * 128;
  const int rowB = (wn * 64 + lr) * 128;
  const int NT = Kdim >> 7;            // 16

  // prologue: stage tile 0 (A: 4 chunks of 32 rows, B: 4 chunks)
  #pragma unroll
  for (int c = 0; c < 4; ++c) {
    async16(gA + (size_t)c * 32 * Kdim, lA + c * 4096 + tid * 16);
    async16(gB + (size_t)c * 32 * Kdim, lB + c * 4096 + tid * 16);
  }
  S_VM0();
  S_BAR();

  for (int t = 0; t < NT; ++t) {
    const int buf = t & 1;
    const char* pA = lA + buf * ASZ + rowA;
    const char* pB = lB + buf * BSZ + rowB;

    long a[4][4], bb[4][4];
    #pragma unroll
    for (int kq = 0; kq < 4; ++kq) {
      #pragma unroll
      for (int ni = 0; ni < 4; ++ni) bb[kq][ni] = *(const long*)(pB + ni * 2048 + kof[kq]);
      #pragma unroll
      for (int mi = 0; mi < 4; ++mi) a[kq][mi] = *(const long*)(pA + mi * 2048 + kof[kq]);
    }
    SCHED_PIN();
    if (t + 1 < NT) {
      const char* gAt = gA + (size_t)(t + 1) * 128;
      const char* gBt = gB + (size_t)(t + 1) * 128;
      char* lAd = lA + (buf ^ 1) * ASZ + tid * 16;
      char* lBd = lB + (buf ^ 1) * BSZ + tid * 16;
      #pragma unroll
      for (int c = 0; c < 4; ++c) {
        async16(gAt + (size_t)c * 32 * Kdim, lAd + c * 4096);
        async16(gBt + (size_t)c * 32 * Kdim, lBd + c * 4096);
      }
    }
    SCHED_PIN();
    #pragma unroll
    for (int kq = 0; kq < 4; ++kq) {
      __builtin_amdgcn_s_setprio(1);
      #pragma unroll
      for (int mi = 0; mi < 4; ++mi)
        #pragma unroll
        for (int ni = 0; ni < 4; ++ni)
          acc[mi][ni] = __builtin_amdgcn_mfma_f32_16x16x32_fp8_fp8(a[kq][mi], bb[kq][ni], acc[mi][ni], 0, 0, 0);
      __builtin_amdgcn_s_setprio(0);
      SCHED_PIN();
    }
    if (t + 1 < NT) S_VM0();
    S_BAR();
  }

  #pragma unroll
  for (int mi = 0; mi < 4; ++mi) {
    const int rbase = m0 + wm * 64 + mi * 16 + (hi << 2);
    #pragma unroll
    for (int ni = 0; ni < 4; ++ni) {
      const int col = n0 + wn * 64 + ni * 16 + (lane & 15);
      #pragma unroll
      for (int r = 0; r < 4; ++r) {
        const size_t off = (size_t)(rbase + r) * DDIM + col;
        out[off] = resid[off] + acc[mi][ni][r] * scl;
      }
    }
  }
}

// --------- fp8 V transpose: vbuf8[8192][1024] -> vTb[b][h][sblk16][d256][s64] ------
__global__ __launch_bounds__(256) void vT8_kernel(const char* __restrict__ vbuf8,
                                                  char* __restrict__ vTb) {
  const int blk = blockIdx.x;          // 512
  const int sblk = blk & 15;
  const int head = (blk >> 4) & 3;
  const int b = blk >> 6;
  const int t = threadIdx.x;
  __shared__ u32 vt[64][66];

  const int s_l = t >> 2, q4 = t & 3;
  const uint4* src = (const uint4*)&vbuf8[(size_t)(b * 1024 + sblk * 64 + s_l) * 1024 +
                                          head * 256 + q4 * 64];
  #pragma unroll
  for (int c = 0; c < 4; ++c) {
    const uint4 ww = src[c];
    vt[s_l][q4 * 16 + c * 4 + 0] = ww.x;
    vt[s_l][q4 * 16 + c * 4 + 1] = ww.y;
    vt[s_l][q4 * 16 + c * 4 + 2] = ww.z;
    vt[s_l][q4 * 16 + c * 4 + 3] = ww.w;
  }
  __syncthreads();
  const int d = t;
  const int wsel = (d & 3) * 8;
  char* dst = vTb + (((size_t)(b * 4 + head) * 16 + sblk) * 256 + d) * 64;
  #pragma unroll
  for (int c = 0; c < 4; ++c) {
    u32 wo[4];
    #pragma unroll
    for (int k = 0; k < 4; ++k) {
      const int s0 = c * 16 + k * 4;
      const u32 r0 = vt[s0 + 0][d >> 2];
      const u32 r1 = vt[s0 + 1][d >> 2];
      const u32 r2 = vt[s0 + 2][d >> 2];
      const u32 r3 = vt[s0 + 3][d >> 2];
      wo[k] = ((r0 >> wsel) & 0xffu) | (((r1 >> wsel) & 0xffu) << 8) |
              (((r2 >> wsel) & 0xffu) << 16) | (((r3 >> wsel) & 0xffu) << 24);
    }
    *(uint4*)(dst + c * 16) = make_uint4(wo[0], wo[1], wo[2], wo[3]);
  }
}

// ------------- MFMA sliding-window attention (W=32) -------------
__global__ __launch_bounds__(256, 2) void attn_mfma(const __bf16* __restrict__ h,
                                                    const char* __restrict__ vTb,
                                                    char* __restrict__ fused8,
                                                    const float* __restrict__ pbm) {
  const int blk = blockIdx.x;          // 256
  const int qblk = blk & 7;
  const int head = (blk >> 3) & 3;
  const int b = blk >> 5;
  const int tid = threadIdx.x;
  const int lane = tid & 63;
  const int w = tid >> 6;
  __shared__ char vt[256 * 176];
  __shared__ char pl[4][32 * 80];

  const float p = pbm[0];
  const float sp = (p > 20.0f) ? p : log1pf(expf(p));

  {
    const int m = qblk * 2;
    const char* base = vTb + ((size_t)(b * 4 + head) * 16) * 16384;
    #pragma unroll
    for (int it = 0; it < 11; ++it) {
      const int U = it * 256 + tid;
      const int d = U / 11;
      const int slot = U - d * 11;
      int sb, so;
      if (slot >= 10)      { sb = m; so = 0; }
      else if (slot < 2)   { sb = m - 1; so = 32 + slot * 16; }
      else if (slot < 6)   { sb = m; so = (slot - 2) * 16; }
      else                 { sb = m + 1; so = (slot - 6) * 16; }
      if (sb < 0) sb = 0;
      async16(base + ((size_t)sb * 256 + d) * 64 + so, vt + U * 16);
    }
  }

  const int col = lane & 15;
  const int hi = lane >> 4;
  const int qb = qblk * 128 + w * 32;
  const int kb = qb - 32;

  f32x4 sc[4][2] = {};
  bf16x8 afr[4], bfr[2];
  #pragma unroll
  for (int mf = 0; mf < 4; ++mf) {
    int key = kb + mf * 16 + col;
    if (key < 0) key = 0;
    afr[mf] = *(const bf16x8*)&h[(size_t)(b * 1024 + key) * HQK + 128 + head * 32 + hi * 8];
  }
  #pragma unroll
  for (int nf = 0; nf < 2; ++nf)
    bfr[nf] = *(const bf16x8*)&h[(size_t)(b * 1024 + qb + nf * 16 + col) * HQK + head * 32 + hi * 8];
  #pragma unroll
  for (int mf = 0; mf < 4; ++mf)
    #pragma unroll
    for (int nf = 0; nf < 2; ++nf)
      sc[mf][nf] = __builtin_amdgcn_mfma_f32_16x16x32_bf16(afr[mf], bfr[nf], sc[mf][nf], 0, 0, 0);

  #pragma unroll
  for (int nf = 0; nf < 2; ++nf) {
    #pragma unroll
    for (int mf = 0; mf < 4; ++mf)
      #pragma unroll
      for (int r = 0; r < 4; ++r) {
        const int delta = mf * 16 + hi * 4 + r - nf * 16 - col - 32;
        const int keyabs = kb + mf * 16 + hi * 4 + r;
        const bool valid = (delta <= 0) & (delta >= -31) & (keyabs >= 0);
        sc[mf][nf][r] = valid ? sc[mf][nf][r] * 0.1767766953f + sp * (float)delta : -1e30f;
      }
    float m = -1e30f;
    #pragma unroll
    for (int mf = 0; mf < 4; ++mf)
      #pragma unroll
      for (int r = 0; r < 4; ++r) m = fmaxf(m, sc[mf][nf][r]);
    m = fmaxf(m, __shfl_xor(m, 16));
    m = fmaxf(m, __shfl_xor(m, 32));
    float s = 0.0f;
    #pragma unroll
    for (int mf = 0; mf < 4; ++mf)
      #pragma unroll
      for (int r = 0; r < 4; ++r) {
        const float e = __expf(sc[mf][nf][r] - m);
        sc[mf][nf][r] = e;
        s += e;
      }
    s += __shfl_xor(s, 16);
    s += __shfl_xor(s, 32);
    const float inv = 1.0f / s;
    #pragma unroll
    for (int mf = 0; mf < 4; ++mf) {
      const u32 pk = pack4_e4m3(sc[mf][nf][0] * inv, sc[mf][nf][1] * inv,
                                sc[mf][nf][2] * inv, sc[mf][nf][3] * inv);
      *(u32*)&pl[w][(nf * 16 + col) * 80 + mf * 16 + hi * 4] = pk;
    }
  }

  __syncthreads();

  const char* ppl = pl[w];
  const int kloc = w * 32;
  f32x4 ao[16][2] = {};
  #pragma unroll
  for (int kf = 0; kf < 2; ++kf) {
    long bfrag[2];
    #pragma unroll
    for (int nf = 0; nf < 2; ++nf)
      bfrag[nf] = *(const long*)&ppl[(nf * 16 + col) * 80 + kf * 32 + hi * 8];
    #pragma unroll
    for (int mf = 0; mf < 16; ++mf) {
      const long af = *(const long*)&vt[(mf * 16 + col) * 176 + kloc + kf * 32 + hi * 8];
      #pragma unroll
      for (int nf = 0; nf < 2; ++nf)
        ao[mf][nf] = __builtin_amdgcn_mfma_f32_16x16x32_fp8_fp8(af, bfrag[nf], ao[mf][nf], 0, 0, 0);
    }
  }

  #pragma unroll
  for (int mf = 0; mf < 16; ++mf)
    #pragma unroll
    for (int nf = 0; nf < 2; ++nf) {
      const u32 pk = pack4_e4m3(ao[mf][nf][0], ao[mf][nf][1], ao[mf][nf][2], ao[mf][nf][3]);
      *(u32*)&fused8[(size_t)(b * 1024 + qb + nf * 16 + col) * EDIM + 1024 +
                     head * 256 + mf * 16 + hi * 4] = pk;
    }
}

// ---------------- host launch ----------------
extern "C" void kernel_launch(void* const* d_in, const int* in_sizes, int n_in,
                              void* d_out, int out_size, void* d_ws, size_t ws_size,
                              hipStream_t stream) {
  const float* x = (const float*)d_in[0];
  const float* norm_w = (const float*)d_in[2];
  const float* expand_w = (const float*)d_in[3];
  const float* project_w = (const float*)d_in[4];
  const float* pbm = (const float*)d_in[5];
  float* out = (float*)d_out;

  char* ws = (char*)d_ws;
  __bf16* xn    = (__bf16*)(ws);                  // 16,777,216
  u32*    xn8   = (u32*)(ws + 16777216);          //  8,388,608
  __bf16* wqk   = (__bf16*)(ws + 25165824);       //    524,288
  char*   wexp8i= (char*)(ws + 25690112);         //  4,194,304 (interleaved, x16)
  char*   wproj8= (char*)(ws + 29884416);         //  2,097,152 (x256)
  __bf16* h     = (__bf16*)(ws + 31981568);       //  4,194,304 (q|k only)
  char*   fused8= (char*)(ws + 36175872);         // 16,777,216
  char*   vbuf8 = (char*)(ws + 52953088);         //  8,388,608
  char*   vTb   = (char*)(ws + 61341696);         //  8,388,608

  ln_kernel<<<MROWS, 256, 0, stream>>>(x, norm_w, xn, xn8);
  cast_kernel<<<256, 256, 0, stream>>>(expand_w, wqk, 65536);
  cast8i_kernel<<<4096, 256, 0, stream>>>(expand_w + 256 * DDIM, (u32*)wexp8i);
  cast8_kernel<<<2048, 256, 0, stream>>>(project_w, (u32*)wproj8, 524288, 256.0f);
  // q/k columns: M=8192, N=256, K=1024 (bf16)
  gemm_bt<<<dim3(64, 2), 256, 0, stream>>>(xn, wqk, h, HQK, DDIM, 0);
  // expand + fused GEGLU: 64 m x 32 n = 2048 blocks, 256 threads (proj-style)
  gemm1glu<<<2048, 256, 0, stream>>>((const char*)xn8, wexp8i, fused8, vbuf8);
  vT8_kernel<<<512, 256, 0, stream>>>(vbuf8, vTb);
  attn_mfma<<<256, 256, 0, stream>>>(h, vTb, fused8, pbm);
  // project: M=8192 (64 tiles) x N=1024 (8 tiles) = 512 blocks, 256 threads
  gemmproj<<<512, 256, 0, stream>>>(fused8, wproj8, out, x, 1.0f / 256.0f);
}

// Round 14
// 127.626 us; speedup vs baseline: 1.1950x; 1.1362x over previous
//
#include <hip/hip_runtime.h>
#include <hip/hip_bf16.h>
#include <hip/hip_fp8.h>

typedef __bf16 bf16x8 __attribute__((ext_vector_type(8)));
typedef __bf16 bf16x4 __attribute__((ext_vector_type(4)));
typedef float f32x4 __attribute__((ext_vector_type(4)));
typedef unsigned int u32;
typedef __attribute__((address_space(3))) u32 lds_u32_t;
typedef __attribute__((address_space(1))) u32 glb_u32_t;

#define MROWS 8192      // B*S
#define DDIM 1024
#define EDIM 2048
#define HQK 256         // h buffer holds only q|k columns

#define S_BAR() asm volatile("s_barrier" ::: "memory")
#define S_VM0() asm volatile("s_waitcnt vmcnt(0)" ::: "memory")
#define SCHED_PIN() __builtin_amdgcn_sched_barrier(0)

__device__ __forceinline__ void async16(const void* g, void* l) {
  __builtin_amdgcn_global_load_lds((const glb_u32_t*)g, (lds_u32_t*)l, 16, 0, 0);
}

__device__ __forceinline__ u32 pack4_e4m3(float f0, float f1, float f2, float f3) {
  __hip_fp8_e4m3 a(f0), b(f1), c(f2), d(f3);
  return (u32)a.__x | ((u32)b.__x << 8) | ((u32)c.__x << 16) | ((u32)d.__x << 24);
}

// ---------------- LayerNorm + fp8 cast (no bf16 xn anymore) ----------------
__global__ __launch_bounds__(256) void ln_kernel(const float* __restrict__ x,
                                                 const float* __restrict__ wgt,
                                                 u32* __restrict__ xn8) {
  const int row = blockIdx.x;
  const int t = threadIdx.x;
  const float4 v = ((const float4*)(x + (size_t)row * DDIM))[t];
  float s = v.x + v.y + v.z + v.w;
  float ss = v.x * v.x + v.y * v.y + v.z * v.z + v.w * v.w;
  #pragma unroll
  for (int o = 32; o > 0; o >>= 1) {
    s += __shfl_down(s, o);
    ss += __shfl_down(ss, o);
  }
  __shared__ float red[8];
  const int lane = t & 63, wv = t >> 6;
  if (lane == 0) { red[wv] = s; red[4 + wv] = ss; }
  __syncthreads();
  s = red[0] + red[1] + red[2] + red[3];
  ss = red[4] + red[5] + red[6] + red[7];
  const float mu = s * (1.0f / 1024.0f);
  const float rstd = rsqrtf(ss * (1.0f / 1024.0f) - mu * mu + 1e-5f);
  const float4 w4 = ((const float4*)wgt)[t];
  xn8[row * 256 + t] = pack4_e4m3((v.x - mu) * rstd * w4.x, (v.y - mu) * rstd * w4.y,
                                  (v.z - mu) * rstd * w4.z, (v.w - mu) * rstd * w4.w);
}

// ---------------- fp32 -> fp8 weight cast (pre-scaled) ----------------
__global__ __launch_bounds__(256) void cast8_kernel(const float* __restrict__ src,
                                                    u32* __restrict__ dst, int n4, float scale) {
  const int i = blockIdx.x * 256 + threadIdx.x;
  if (i < n4) {
    const float4 v = ((const float4*)src)[i];
    dst[i] = pack4_e4m3(v.x * scale, v.y * scale, v.z * scale, v.w * scale);
  }
}

// ------ fp32 -> fp8 interleaved expand-weight cast (lin/pre frag pairs) ------
__global__ __launch_bounds__(256) void cast8i_kernel(const float* __restrict__ src,
                                                     u32* __restrict__ dst) {
  const int i = blockIdx.x * 256 + threadIdx.x;   // 4096*256
  const int rp = i >> 8, k4 = i & 255;
  const int c = ((rp >> 5) << 4) | (rp & 15);
  const int pre = (rp >> 4) & 1;
  const float4 v = *(const float4*)(src + ((size_t)(pre * 2048 + c)) * 1024 + k4 * 4);
  dst[i] = pack4_e4m3(v.x * 16.0f, v.y * 16.0f, v.z * 16.0f, v.w * 16.0f);
}

// -------- fp8 q/k GEMM: h[.,0:256] = xn8 * wqk8^T / 16 (bf16 out) --------
// 256 threads, 4 waves (2Mx2N), BM=64, BN=128, BK=128, 8-unit XOR swizzle.
__global__ __launch_bounds__(256, 2) void gemmqk(const char* __restrict__ A8,
                                                 const char* __restrict__ B8,
                                                 __bf16* __restrict__ h) {
  constexpr int ASZ = 64 * 128;    // 8KB
  constexpr int BSZ = 128 * 128;   // 16KB
  constexpr int Kdim = 1024;
  __shared__ alignas(16) char As[2 * ASZ];
  __shared__ alignas(16) char Bs[2 * BSZ];

  const int tid = threadIdx.x;
  const int lane = tid & 63;
  const int w = tid >> 6;
  const int wm = w >> 1, wn = w & 1;

  const int qq = gridDim.x >> 3;
  const int wgid = (blockIdx.x & 7) * qq + (blockIdx.x >> 3);
  const int m0 = (wgid >> 1) * 64;
  const int n0 = (wgid & 1) * 128;

  f32x4 acc[2][4] = {};

  const int rowS = tid >> 3;           // 0..31 (+32 per chunk)
  const int uS = tid & 7;
  const int luS = uS ^ (rowS & 7);
  const char* gA = A8 + (size_t)(m0 + rowS) * Kdim + luS * 16;
  const char* gB = B8 + (size_t)(n0 + rowS) * Kdim + luS * 16;
  char* lA = (char*)As;
  char* lB = (char*)Bs;

  const int lr = lane & 15;
  const int hi = lane >> 4;
  int kof[4];
  #pragma unroll
  for (int kq = 0; kq < 4; ++kq)
    kof[kq] = (((kq * 2 + (hi >> 1)) ^ (lr & 7)) << 4) + (hi & 1) * 8;
  const int rowA = (wm * 32 + lr) * 128;
  const int rowB = (wn * 64 + lr) * 128;
  const int NT = Kdim >> 7;            // 8

  #pragma unroll
  for (int c = 0; c < 2; ++c) async16(gA + (size_t)c * 32 * Kdim, lA + c * 4096 + tid * 16);
  #pragma unroll
  for (int c = 0; c < 4; ++c) async16(gB + (size_t)c * 32 * Kdim, lB + c * 4096 + tid * 16);
  S_VM0();
  S_BAR();

  for (int t = 0; t < NT; ++t) {
    const int buf = t & 1;
    const char* pA = lA + buf * ASZ + rowA;
    const char* pB = lB + buf * BSZ + rowB;

    long a[4][2], bb[4][4];
    #pragma unroll
    for (int kq = 0; kq < 4; ++kq) {
      #pragma unroll
      for (int ni = 0; ni < 4; ++ni) bb[kq][ni] = *(const long*)(pB + ni * 2048 + kof[kq]);
      #pragma unroll
      for (int mi = 0; mi < 2; ++mi) a[kq][mi] = *(const long*)(pA + mi * 2048 + kof[kq]);
    }
    SCHED_PIN();
    if (t + 1 < NT) {
      const char* gAt = gA + (size_t)(t + 1) * 128;
      const char* gBt = gB + (size_t)(t + 1) * 128;
      char* lAd = lA + (buf ^ 1) * ASZ + tid * 16;
      char* lBd = lB + (buf ^ 1) * BSZ + tid * 16;
      #pragma unroll
      for (int c = 0; c < 2; ++c) async16(gAt + (size_t)c * 32 * Kdim, lAd + c * 4096);
      #pragma unroll
      for (int c = 0; c < 4; ++c) async16(gBt + (size_t)c * 32 * Kdim, lBd + c * 4096);
    }
    SCHED_PIN();
    #pragma unroll
    for (int kq = 0; kq < 4; ++kq) {
      __builtin_amdgcn_s_setprio(1);
      #pragma unroll
      for (int mi = 0; mi < 2; ++mi)
        #pragma unroll
        for (int ni = 0; ni < 4; ++ni)
          acc[mi][ni] = __builtin_amdgcn_mfma_f32_16x16x32_fp8_fp8(a[kq][mi], bb[kq][ni], acc[mi][ni], 0, 0, 0);
      __builtin_amdgcn_s_setprio(0);
      SCHED_PIN();
    }
    if (t + 1 < NT) S_VM0();
    S_BAR();
  }

  #pragma unroll
  for (int mi = 0; mi < 2; ++mi) {
    const int rbase = m0 + wm * 32 + mi * 16 + (hi << 2);
    #pragma unroll
    for (int ni = 0; ni < 4; ++ni) {
      const int col = n0 + wn * 64 + ni * 16 + (lane & 15);
      #pragma unroll
      for (int r = 0; r < 4; ++r)
        h[(size_t)(rbase + r) * HQK + col] = (__bf16)(acc[mi][ni][r] * 0.0625f);
    }
  }
}

// ------- fp8 GEMM + fused GEGLU epilogue, TRANSPOSED output (r11-proven) -------
// 512 threads, 8 waves (2Mx4N), BM=128, BN=256 (interleaved lin/pre), BK=64.
__global__ __launch_bounds__(512, 4) void gemm1glu(const char* __restrict__ A8,
                                                   const char* __restrict__ B8,
                                                   char* __restrict__ fused8,
                                                   char* __restrict__ vbuf8) {
  constexpr int ASZ = 128 * 64;
  constexpr int BSZ = 256 * 64;
  constexpr int Kdim = 1024;
  __shared__ alignas(16) char As[2 * ASZ];
  __shared__ alignas(16) char Bs[2 * BSZ];

  const int tid = threadIdx.x;
  const int lane = tid & 63;
  const int w = tid >> 6;
  const int wm = w >> 2, wn = w & 3;

  const int qq = gridDim.x >> 3;
  const int wgid = (blockIdx.x & 7) * qq + (blockIdx.x >> 3);
  const int m0 = (wgid / 16) * 128;
  const int nblk = wgid % 16;
  const int n0r = nblk * 256;          // weight-row base

  f32x4 acc[4][4] = {};                // acc[nf][mf] (transposed)

  const int rowS = (tid >> 2) & 127;
  const int uS = tid & 3;
  const int luS = uS ^ ((rowS >> 1) & 3);
  const char* gA = A8 + (size_t)(m0 + rowS) * Kdim + luS * 16;
  const char* gB = B8 + (size_t)(n0r + rowS) * Kdim + luS * 16;
  char* lA = (char*)As;
  char* lB = (char*)Bs;

  const int lr = lane & 15;
  const int hi = lane >> 4;
  const int sw = (lr >> 1) & 3;
  const int kof0 = ((((hi >> 1)) ^ sw) << 4) + (hi & 1) * 8;
  const int kof1 = (((2 + (hi >> 1)) ^ sw) << 4) + (hi & 1) * 8;
  const int rowA = (wm * 64 + lr) * 64;
  const int rowB = (wn * 64 + lr) * 64;
  const int NT = Kdim >> 6;

  async16(gA, lA + tid * 16);
  async16(gB, lB + tid * 16);
  async16(gB + (size_t)128 * Kdim, lB + 8192 + tid * 16);
  S_VM0();
  S_BAR();

  for (int t = 0; t < NT; ++t) {
    const int buf = t & 1;
    const char* pA = lA + buf * ASZ + rowA;
    const char* pB = lB + buf * BSZ + rowB;

    long a0[4], b0[4], a1[4], b1[4];
    #pragma unroll
    for (int ni = 0; ni < 4; ++ni) b0[ni] = *(const long*)(pB + ni * 1024 + kof0);
    #pragma unroll
    for (int mi = 0; mi < 4; ++mi) a0[mi] = *(const long*)(pA + mi * 1024 + kof0);
    SCHED_PIN();
    #pragma unroll
    for (int ni = 0; ni < 4; ++ni) b1[ni] = *(const long*)(pB + ni * 1024 + kof1);
    #pragma unroll
    for (int mi = 0; mi < 4; ++mi) a1[mi] = *(const long*)(pA + mi * 1024 + kof1);
    SCHED_PIN();
    if (t + 1 < NT) {
      const char* gAt = gA + (size_t)(t + 1) * 64;
      const char* gBt = gB + (size_t)(t + 1) * 64;
      char* lAd = lA + (buf ^ 1) * ASZ + tid * 16;
      char* lBd = lB + (buf ^ 1) * BSZ + tid * 16;
      async16(gAt, lAd);
      async16(gBt, lBd);
      async16(gBt + (size_t)128 * Kdim, lBd + 8192);
    }
    SCHED_PIN();
    __builtin_amdgcn_s_setprio(1);
    #pragma unroll
    for (int ni = 0; ni < 4; ++ni)
      #pragma unroll
      for (int mi = 0; mi < 4; ++mi)
        acc[ni][mi] = __builtin_amdgcn_mfma_f32_16x16x32_fp8_fp8(b0[ni], a0[mi], acc[ni][mi], 0, 0, 0);
    __builtin_amdgcn_s_setprio(0);
    SCHED_PIN();
    __builtin_amdgcn_s_setprio(1);
    #pragma unroll
    for (int ni = 0; ni < 4; ++ni)
      #pragma unroll
      for (int mi = 0; mi < 4; ++mi)
        acc[ni][mi] = __builtin_amdgcn_mfma_f32_16x16x32_fp8_fp8(b1[ni], a1[mi], acc[ni][mi], 0, 0, 0);
    __builtin_amdgcn_s_setprio(0);
    SCHED_PIN();
    if (t + 1 < NT) S_VM0();
    S_BAR();
  }

  #pragma unroll
  for (int p = 0; p < 2; ++p) {
    const int g = nblk * 8 + wn * 2 + p;
    const int cb = g * 16 + hi * 4;
    const bool isv = nblk >= 8;
    #pragma unroll
    for (int mf = 0; mf < 4; ++mf) {
      const int m = m0 + wm * 64 + mf * 16 + (lane & 15);
      float gg[4];
      #pragma unroll
      for (int r = 0; r < 4; ++r) {
        const float l = acc[2 * p][mf][r] * 0.0625f;
        const float q = acc[2 * p + 1][mf][r] * 0.0625f;
        gg[r] = l * 0.5f * q * (1.0f + erff(q * 0.70710678118f));
      }
      const u32 pk = pack4_e4m3(gg[0], gg[1], gg[2], gg[3]);
      if (isv) *(u32*)&vbuf8[(size_t)m * 1024 + (cb - 1024)] = pk;
      else     *(u32*)&fused8[(size_t)m * EDIM + cb] = pk;
    }
  }
}

// ---------------- fp8 project GEMM, 256 threads, BM=128 BN=128 BK=128 --------
__global__ __launch_bounds__(256, 2) void gemmproj(const char* __restrict__ A8,
                                                   const char* __restrict__ B8,
                                                   float* __restrict__ out,
                                                   const float* __restrict__ resid,
                                                   float scl) {
  constexpr int ASZ = 128 * 128;   // 16KB
  constexpr int BSZ = 128 * 128;   // 16KB
  constexpr int Kdim = 2048;
  __shared__ alignas(16) char As[2 * ASZ];
  __shared__ alignas(16) char Bs[2 * BSZ];

  const int tid = threadIdx.x;
  const int lane = tid & 63;
  const int w = tid >> 6;
  const int wm = w >> 1, wn = w & 1;

  const int qq = gridDim.x >> 3;
  const int wgid = (blockIdx.x & 7) * qq + (blockIdx.x >> 3);
  const int m0 = (wgid / 8) * 128;
  const int n0 = (wgid % 8) * 128;

  f32x4 acc[4][4] = {};

  const int rowS = tid >> 3;
  const int uS = tid & 7;
  const int luS = uS ^ (rowS & 7);
  const char* gA = A8 + (size_t)(m0 + rowS) * Kdim + luS * 16;
  const char* gB = B8 + (size_t)(n0 + rowS) * Kdim + luS * 16;
  char* lA = (char*)As;
  char* lB = (char*)Bs;

  const int lr = lane & 15;
  const int hi = lane >> 4;
  int kof[4];
  #pragma unroll
  for (int kq = 0; kq < 4; ++kq)
    kof[kq] = (((kq * 2 + (hi >> 1)) ^ (lr & 7)) << 4) + (hi & 1) * 8;
  const int rowA = (wm * 64 + lr) * 128;
  const int rowB = (wn * 64 + lr) * 128;
  const int NT = Kdim >> 7;            // 16

  #pragma unroll
  for (int c = 0; c < 4; ++c) {
    async16(gA + (size_t)c * 32 * Kdim, lA + c * 4096 + tid * 16);
    async16(gB + (size_t)c * 32 * Kdim, lB + c * 4096 + tid * 16);
  }
  S_VM0();
  S_BAR();

  for (int t = 0; t < NT; ++t) {
    const int buf = t & 1;
    const char* pA = lA + buf * ASZ + rowA;
    const char* pB = lB + buf * BSZ + rowB;

    long a[4][4], bb[4][4];
    #pragma unroll
    for (int kq = 0; kq < 4; ++kq) {
      #pragma unroll
      for (int ni = 0; ni < 4; ++ni) bb[kq][ni] = *(const long*)(pB + ni * 2048 + kof[kq]);
      #pragma unroll
      for (int mi = 0; mi < 4; ++mi) a[kq][mi] = *(const long*)(pA + mi * 2048 + kof[kq]);
    }
    SCHED_PIN();
    if (t + 1 < NT) {
      const char* gAt = gA + (size_t)(t + 1) * 128;
      const char* gBt = gB + (size_t)(t + 1) * 128;
      char* lAd = lA + (buf ^ 1) * ASZ + tid * 16;
      char* lBd = lB + (buf ^ 1) * BSZ + tid * 16;
      #pragma unroll
      for (int c = 0; c < 4; ++c) {
        async16(gAt + (size_t)c * 32 * Kdim, lAd + c * 4096);
        async16(gBt + (size_t)c * 32 * Kdim, lBd + c * 4096);
      }
    }
    SCHED_PIN();
    #pragma unroll
    for (int kq = 0; kq < 4; ++kq) {
      __builtin_amdgcn_s_setprio(1);
      #pragma unroll
      for (int mi = 0; mi < 4; ++mi)
        #pragma unroll
        for (int ni = 0; ni < 4; ++ni)
          acc[mi][ni] = __builtin_amdgcn_mfma_f32_16x16x32_fp8_fp8(a[kq][mi], bb[kq][ni], acc[mi][ni], 0, 0, 0);
      __builtin_amdgcn_s_setprio(0);
      SCHED_PIN();
    }
    if (t + 1 < NT) S_VM0();
    S_BAR();
  }

  #pragma unroll
  for (int mi = 0; mi < 4; ++mi) {
    const int rbase = m0 + wm * 64 + mi * 16 + (hi << 2);
    #pragma unroll
    for (int ni = 0; ni < 4; ++ni) {
      const int col = n0 + wn * 64 + ni * 16 + (lane & 15);
      #pragma unroll
      for (int r = 0; r < 4; ++r) {
        const size_t off = (size_t)(rbase + r) * DDIM + col;
        out[off] = resid[off] + acc[mi][ni][r] * scl;
      }
    }
  }
}

// --------- fp8 V transpose: vbuf8[8192][1024] -> vTb[b][h][sblk16][d256][s64] ------
__global__ __launch_bounds__(256) void vT8_kernel(const char* __restrict__ vbuf8,
                                                  char* __restrict__ vTb) {
  const int blk = blockIdx.x;          // 512
  const int sblk = blk & 15;
  const int head = (blk >> 4) & 3;
  const int b = blk >> 6;
  const int t = threadIdx.x;
  __shared__ u32 vt[64][66];

  const int s_l = t >> 2, q4 = t & 3;
  const uint4* src = (const uint4*)&vbuf8[(size_t)(b * 1024 + sblk * 64 + s_l) * 1024 +
                                          head * 256 + q4 * 64];
  #pragma unroll
  for (int c = 0; c < 4; ++c) {
    const uint4 ww = src[c];
    vt[s_l][q4 * 16 + c * 4 + 0] = ww.x;
    vt[s_l][q4 * 16 + c * 4 + 1] = ww.y;
    vt[s_l][q4 * 16 + c * 4 + 2] = ww.z;
    vt[s_l][q4 * 16 + c * 4 + 3] = ww.w;
  }
  __syncthreads();
  const int d = t;
  const int wsel = (d & 3) * 8;
  char* dst = vTb + (((size_t)(b * 4 + head) * 16 + sblk) * 256 + d) * 64;
  #pragma unroll
  for (int c = 0; c < 4; ++c) {
    u32 wo[4];
    #pragma unroll
    for (int k = 0; k < 4; ++k) {
      const int s0 = c * 16 + k * 4;
      const u32 r0 = vt[s0 + 0][d >> 2];
      const u32 r1 = vt[s0 + 1][d >> 2];
      const u32 r2 = vt[s0 + 2][d >> 2];
      const u32 r3 = vt[s0 + 3][d >> 2];
      wo[k] = ((r0 >> wsel) & 0xffu) | (((r1 >> wsel) & 0xffu) << 8) |
              (((r2 >> wsel) & 0xffu) << 16) | (((r3 >> wsel) & 0xffu) << 24);
    }
    *(uint4*)(dst + c * 16) = make_uint4(wo[0], wo[1], wo[2], wo[3]);
  }
}

// ------------- MFMA sliding-window attention (W=32) -------------
__global__ __launch_bounds__(256, 2) void attn_mfma(const __bf16* __restrict__ h,
                                                    const char* __restrict__ vTb,
                                                    char* __restrict__ fused8,
                                                    const float* __restrict__ pbm) {
  const int blk = blockIdx.x;          // 256
  const int qblk = blk & 7;
  const int head = (blk >> 3) & 3;
  const int b = blk >> 5;
  const int tid = threadIdx.x;
  const int lane = tid & 63;
  const int w = tid >> 6;
  __shared__ char vt[256 * 176];
  __shared__ char pl[4][32 * 80];

  const float p = pbm[0];
  const float sp = (p > 20.0f) ? p : log1pf(expf(p));

  {
    const int m = qblk * 2;
    const char* base = vTb + ((size_t)(b * 4 + head) * 16) * 16384;
    #pragma unroll
    for (int it = 0; it < 11; ++it) {
      const int U = it * 256 + tid;
      const int d = U / 11;
      const int slot = U - d * 11;
      int sb, so;
      if (slot >= 10)      { sb = m; so = 0; }
      else if (slot < 2)   { sb = m - 1; so = 32 + slot * 16; }
      else if (slot < 6)   { sb = m; so = (slot - 2) * 16; }
      else                 { sb = m + 1; so = (slot - 6) * 16; }
      if (sb < 0) sb = 0;
      async16(base + ((size_t)sb * 256 + d) * 64 + so, vt + U * 16);
    }
  }

  const int col = lane & 15;
  const int hi = lane >> 4;
  const int qb = qblk * 128 + w * 32;
  const int kb = qb - 32;

  f32x4 sc[4][2] = {};
  bf16x8 afr[4], bfr[2];
  #pragma unroll
  for (int mf = 0; mf < 4; ++mf) {
    int key = kb + mf * 16 + col;
    if (key < 0) key = 0;
    afr[mf] = *(const bf16x8*)&h[(size_t)(b * 1024 + key) * HQK + 128 + head * 32 + hi * 8];
  }
  #pragma unroll
  for (int nf = 0; nf < 2; ++nf)
    bfr[nf] = *(const bf16x8*)&h[(size_t)(b * 1024 + qb + nf * 16 + col) * HQK + head * 32 + hi * 8];
  #pragma unroll
  for (int mf = 0; mf < 4; ++mf)
    #pragma unroll
    for (int nf = 0; nf < 2; ++nf)
      sc[mf][nf] = __builtin_amdgcn_mfma_f32_16x16x32_bf16(afr[mf], bfr[nf], sc[mf][nf], 0, 0, 0);

  #pragma unroll
  for (int nf = 0; nf < 2; ++nf) {
    #pragma unroll
    for (int mf = 0; mf < 4; ++mf)
      #pragma unroll
      for (int r = 0; r < 4; ++r) {
        const int delta = mf * 16 + hi * 4 + r - nf * 16 - col - 32;
        const int keyabs = kb + mf * 16 + hi * 4 + r;
        const bool valid = (delta <= 0) & (delta >= -31) & (keyabs >= 0);
        sc[mf][nf][r] = valid ? sc[mf][nf][r] * 0.1767766953f + sp * (float)delta : -1e30f;
      }
    float m = -1e30f;
    #pragma unroll
    for (int mf = 0; mf < 4; ++mf)
      #pragma unroll
      for (int r = 0; r < 4; ++r) m = fmaxf(m, sc[mf][nf][r]);
    m = fmaxf(m, __shfl_xor(m, 16));
    m = fmaxf(m, __shfl_xor(m, 32));
    float s = 0.0f;
    #pragma unroll
    for (int mf = 0; mf < 4; ++mf)
      #pragma unroll
      for (int r = 0; r < 4; ++r) {
        const float e = __expf(sc[mf][nf][r] - m);
        sc[mf][nf][r] = e;
        s += e;
      }
    s += __shfl_xor(s, 16);
    s += __shfl_xor(s, 32);
    const float inv = 1.0f / s;
    #pragma unroll
    for (int mf = 0; mf < 4; ++mf) {
      const u32 pk = pack4_e4m3(sc[mf][nf][0] * inv, sc[mf][nf][1] * inv,
                                sc[mf][nf][2] * inv, sc[mf][nf][3] * inv);
      *(u32*)&pl[w][(nf * 16 + col) * 80 + mf * 16 + hi * 4] = pk;
    }
  }

  __syncthreads();

  const char* ppl = pl[w];
  const int kloc = w * 32;
  f32x4 ao[16][2] = {};
  #pragma unroll
  for (int kf = 0; kf < 2; ++kf) {
    long bfrag[2];
    #pragma unroll
    for (int nf = 0; nf < 2; ++nf)
      bfrag[nf] = *(const long*)&ppl[(nf * 16 + col) * 80 + kf * 32 + hi * 8];
    #pragma unroll
    for (int mf = 0; mf < 16; ++mf) {
      const long af = *(const long*)&vt[(mf * 16 + col) * 176 + kloc + kf * 32 + hi * 8];
      #pragma unroll
      for (int nf = 0; nf < 2; ++nf)
        ao[mf][nf] = __builtin_amdgcn_mfma_f32_16x16x32_fp8_fp8(af, bfrag[nf], ao[mf][nf], 0, 0, 0);
    }
  }

  #pragma unroll
  for (int mf = 0; mf < 16; ++mf)
    #pragma unroll
    for (int nf = 0; nf < 2; ++nf) {
      const u32 pk = pack4_e4m3(ao[mf][nf][0], ao[mf][nf][1], ao[mf][nf][2], ao[mf][nf][3]);
      *(u32*)&fused8[(size_t)(b * 1024 + qb + nf * 16 + col) * EDIM + 1024 +
                     head * 256 + mf * 16 + hi * 4] = pk;
    }
}

// ---------------- host launch ----------------
extern "C" void kernel_launch(void* const* d_in, const int* in_sizes, int n_in,
                              void* d_out, int out_size, void* d_ws, size_t ws_size,
                              hipStream_t stream) {
  const float* x = (const float*)d_in[0];
  const float* norm_w = (const float*)d_in[2];
  const float* expand_w = (const float*)d_in[3];
  const float* project_w = (const float*)d_in[4];
  const float* pbm = (const float*)d_in[5];
  float* out = (float*)d_out;

  char* ws = (char*)d_ws;
  u32*    xn8   = (u32*)(ws);                     //  8,388,608
  char*   wqk8  = (char*)(ws + 8388608);          //    262,144 (x16)
  char*   wexp8i= (char*)(ws + 8650752);          //  4,194,304 (interleaved, x16)
  char*   wproj8= (char*)(ws + 12845056);         //  2,097,152 (x256)
  __bf16* h     = (__bf16*)(ws + 14942208);       //  4,194,304 (q|k only)
  char*   fused8= (char*)(ws + 19136512);         // 16,777,216
  char*   vbuf8 = (char*)(ws + 35913728);         //  8,388,608
  char*   vTb   = (char*)(ws + 44302336);         //  8,388,608
  // total 52,690,944 bytes

  ln_kernel<<<MROWS, 256, 0, stream>>>(x, norm_w, xn8);
  cast8_kernel<<<256, 256, 0, stream>>>(expand_w, (u32*)wqk8, 65536, 16.0f);
  cast8i_kernel<<<4096, 256, 0, stream>>>(expand_w + 256 * DDIM, (u32*)wexp8i);
  cast8_kernel<<<2048, 256, 0, stream>>>(project_w, (u32*)wproj8, 524288, 256.0f);
  // q/k columns: M=8192, N=256, K=1024 fp8 -> 128 m x 2 n = 256 blocks
  gemmqk<<<256, 256, 0, stream>>>((const char*)xn8, wqk8, h);
  // expand + fused GEGLU: 64 m x 16 n = 1024 blocks, 512 threads (r11-proven)
  gemm1glu<<<1024, 512, 0, stream>>>((const char*)xn8, wexp8i, fused8, vbuf8);
  vT8_kernel<<<512, 256, 0, stream>>>(vbuf8, vTb);
  attn_mfma<<<256, 256, 0, stream>>>(h, vTb, fused8, pbm);
  // project: M=8192 (64 tiles) x N=1024 (8 tiles) = 512 blocks
  gemmproj<<<512, 256, 0, stream>>>(fused8, wproj8, out, x, 1.0f / 256.0f);
}

// Round 15
// 127.359 us; speedup vs baseline: 1.1975x; 1.0021x over previous
//
#include <hip/hip_runtime.h>
#include <hip/hip_bf16.h>
#include <hip/hip_fp8.h>

typedef __bf16 bf16x8 __attribute__((ext_vector_type(8)));
typedef __bf16 bf16x4 __attribute__((ext_vector_type(4)));
typedef float f32x4 __attribute__((ext_vector_type(4)));
typedef unsigned int u32;
typedef __attribute__((address_space(3))) u32 lds_u32_t;
typedef __attribute__((address_space(1))) u32 glb_u32_t;

#define MROWS 8192      // B*S
#define DDIM 1024
#define EDIM 2048
#define HQK 256         // h buffer holds only q|k columns

#define S_BAR() asm volatile("s_barrier" ::: "memory")
#define S_VM0() asm volatile("s_waitcnt vmcnt(0)" ::: "memory")
#define SCHED_PIN() __builtin_amdgcn_sched_barrier(0)

__device__ __forceinline__ void async16(const void* g, void* l) {
  __builtin_amdgcn_global_load_lds((const glb_u32_t*)g, (lds_u32_t*)l, 16, 0, 0);
}

__device__ __forceinline__ u32 pack4_e4m3(float f0, float f1, float f2, float f3) {
  __hip_fp8_e4m3 a(f0), b(f1), c(f2), d(f3);
  return (u32)a.__x | ((u32)b.__x << 8) | ((u32)c.__x << 16) | ((u32)d.__x << 24);
}

// ---------------- LayerNorm + fp8 cast (no bf16 xn anymore) ----------------
__global__ __launch_bounds__(256) void ln_kernel(const float* __restrict__ x,
                                                 const float* __restrict__ wgt,
                                                 u32* __restrict__ xn8) {
  const int row = blockIdx.x;
  const int t = threadIdx.x;
  const float4 v = ((const float4*)(x + (size_t)row * DDIM))[t];
  float s = v.x + v.y + v.z + v.w;
  float ss = v.x * v.x + v.y * v.y + v.z * v.z + v.w * v.w;
  #pragma unroll
  for (int o = 32; o > 0; o >>= 1) {
    s += __shfl_down(s, o);
    ss += __shfl_down(ss, o);
  }
  __shared__ float red[8];
  const int lane = t & 63, wv = t >> 6;
  if (lane == 0) { red[wv] = s; red[4 + wv] = ss; }
  __syncthreads();
  s = red[0] + red[1] + red[2] + red[3];
  ss = red[4] + red[5] + red[6] + red[7];
  const float mu = s * (1.0f / 1024.0f);
  const float rstd = rsqrtf(ss * (1.0f / 1024.0f) - mu * mu + 1e-5f);
  const float4 w4 = ((const float4*)wgt)[t];
  xn8[row * 256 + t] = pack4_e4m3((v.x - mu) * rstd * w4.x, (v.y - mu) * rstd * w4.y,
                                  (v.z - mu) * rstd * w4.z, (v.w - mu) * rstd * w4.w);
}

// ---------------- fp32 -> fp8 weight cast (pre-scaled) ----------------
__global__ __launch_bounds__(256) void cast8_kernel(const float* __restrict__ src,
                                                    u32* __restrict__ dst, int n4, float scale) {
  const int i = blockIdx.x * 256 + threadIdx.x;
  if (i < n4) {
    const float4 v = ((const float4*)src)[i];
    dst[i] = pack4_e4m3(v.x * scale, v.y * scale, v.z * scale, v.w * scale);
  }
}

// ------ fp32 -> fp8 interleaved expand-weight cast (lin/pre frag pairs) ------
__global__ __launch_bounds__(256) void cast8i_kernel(const float* __restrict__ src,
                                                     u32* __restrict__ dst) {
  const int i = blockIdx.x * 256 + threadIdx.x;   // 4096*256
  const int rp = i >> 8, k4 = i & 255;
  const int c = ((rp >> 5) << 4) | (rp & 15);
  const int pre = (rp >> 4) & 1;
  const float4 v = *(const float4*)(src + ((size_t)(pre * 2048 + c)) * 1024 + k4 * 4);
  dst[i] = pack4_e4m3(v.x * 16.0f, v.y * 16.0f, v.z * 16.0f, v.w * 16.0f);
}

// -------- fp8 q/k GEMM: h[.,0:256] = xn8 * wqk8^T / 16 (bf16 out) --------
// 256 threads, 4 waves (2Mx2N), BM=64, BN=128, BK=128, 8-unit XOR swizzle.
__global__ __launch_bounds__(256, 2) void gemmqk(const char* __restrict__ A8,
                                                 const char* __restrict__ B8,
                                                 __bf16* __restrict__ h) {
  constexpr int ASZ = 64 * 128;    // 8KB
  constexpr int BSZ = 128 * 128;   // 16KB
  constexpr int Kdim = 1024;
  __shared__ alignas(16) char As[2 * ASZ];
  __shared__ alignas(16) char Bs[2 * BSZ];

  const int tid = threadIdx.x;
  const int lane = tid & 63;
  const int w = tid >> 6;
  const int wm = w >> 1, wn = w & 1;

  const int qq = gridDim.x >> 3;
  const int wgid = (blockIdx.x & 7) * qq + (blockIdx.x >> 3);
  const int m0 = (wgid >> 1) * 64;
  const int n0 = (wgid & 1) * 128;

  f32x4 acc[2][4] = {};

  const int rowS = tid >> 3;           // 0..31 (+32 per chunk)
  const int uS = tid & 7;
  const int luS = uS ^ (rowS & 7);
  const char* gA = A8 + (size_t)(m0 + rowS) * Kdim + luS * 16;
  const char* gB = B8 + (size_t)(n0 + rowS) * Kdim + luS * 16;
  char* lA = (char*)As;
  char* lB = (char*)Bs;

  const int lr = lane & 15;
  const int hi = lane >> 4;
  int kof[4];
  #pragma unroll
  for (int kq = 0; kq < 4; ++kq)
    kof[kq] = (((kq * 2 + (hi >> 1)) ^ (lr & 7)) << 4) + (hi & 1) * 8;
  const int rowA = (wm * 32 + lr) * 128;
  const int rowB = (wn * 64 + lr) * 128;
  const int NT = Kdim >> 7;            // 8

  #pragma unroll
  for (int c = 0; c < 2; ++c) async16(gA + (size_t)c * 32 * Kdim, lA + c * 4096 + tid * 16);
  #pragma unroll
  for (int c = 0; c < 4; ++c) async16(gB + (size_t)c * 32 * Kdim, lB + c * 4096 + tid * 16);
  S_VM0();
  S_BAR();

  for (int t = 0; t < NT; ++t) {
    const int buf = t & 1;
    const char* pA = lA + buf * ASZ + rowA;
    const char* pB = lB + buf * BSZ + rowB;

    long a[4][2], bb[4][4];
    #pragma unroll
    for (int kq = 0; kq < 4; ++kq) {
      #pragma unroll
      for (int ni = 0; ni < 4; ++ni) bb[kq][ni] = *(const long*)(pB + ni * 2048 + kof[kq]);
      #pragma unroll
      for (int mi = 0; mi < 2; ++mi) a[kq][mi] = *(const long*)(pA + mi * 2048 + kof[kq]);
    }
    SCHED_PIN();
    if (t + 1 < NT) {
      const char* gAt = gA + (size_t)(t + 1) * 128;
      const char* gBt = gB + (size_t)(t + 1) * 128;
      char* lAd = lA + (buf ^ 1) * ASZ + tid * 16;
      char* lBd = lB + (buf ^ 1) * BSZ + tid * 16;
      #pragma unroll
      for (int c = 0; c < 2; ++c) async16(gAt + (size_t)c * 32 * Kdim, lAd + c * 4096);
      #pragma unroll
      for (int c = 0; c < 4; ++c) async16(gBt + (size_t)c * 32 * Kdim, lBd + c * 4096);
    }
    SCHED_PIN();
    #pragma unroll
    for (int kq = 0; kq < 4; ++kq) {
      __builtin_amdgcn_s_setprio(1);
      #pragma unroll
      for (int mi = 0; mi < 2; ++mi)
        #pragma unroll
        for (int ni = 0; ni < 4; ++ni)
          acc[mi][ni] = __builtin_amdgcn_mfma_f32_16x16x32_fp8_fp8(a[kq][mi], bb[kq][ni], acc[mi][ni], 0, 0, 0);
      __builtin_amdgcn_s_setprio(0);
      SCHED_PIN();
    }
    if (t + 1 < NT) S_VM0();
    S_BAR();
  }

  #pragma unroll
  for (int mi = 0; mi < 2; ++mi) {
    const int rbase = m0 + wm * 32 + mi * 16 + (hi << 2);
    #pragma unroll
    for (int ni = 0; ni < 4; ++ni) {
      const int col = n0 + wn * 64 + ni * 16 + (lane & 15);
      #pragma unroll
      for (int r = 0; r < 4; ++r)
        h[(size_t)(rbase + r) * HQK + col] = (__bf16)(acc[mi][ni][r] * 0.0625f);
    }
  }
}

// ------- fp8 GEMM + fused GEGLU epilogue, TRANSPOSED output (r11-proven) -------
// 512 threads, 8 waves (2Mx4N), BM=128, BN=256 (interleaved lin/pre), BK=64.
__global__ __launch_bounds__(512, 4) void gemm1glu(const char* __restrict__ A8,
                                                   const char* __restrict__ B8,
                                                   char* __restrict__ fused8,
                                                   char* __restrict__ vbuf8) {
  constexpr int ASZ = 128 * 64;
  constexpr int BSZ = 256 * 64;
  constexpr int Kdim = 1024;
  __shared__ alignas(16) char As[2 * ASZ];
  __shared__ alignas(16) char Bs[2 * BSZ];

  const int tid = threadIdx.x;
  const int lane = tid & 63;
  const int w = tid >> 6;
  const int wm = w >> 2, wn = w & 3;

  const int qq = gridDim.x >> 3;
  const int wgid = (blockIdx.x & 7) * qq + (blockIdx.x >> 3);
  const int m0 = (wgid / 16) * 128;
  const int nblk = wgid % 16;
  const int n0r = nblk * 256;          // weight-row base

  f32x4 acc[4][4] = {};                // acc[nf][mf] (transposed)

  const int rowS = (tid >> 2) & 127;
  const int uS = tid & 3;
  const int luS = uS ^ ((rowS >> 1) & 3);
  const char* gA = A8 + (size_t)(m0 + rowS) * Kdim + luS * 16;
  const char* gB = B8 + (size_t)(n0r + rowS) * Kdim + luS * 16;
  char* lA = (char*)As;
  char* lB = (char*)Bs;

  const int lr = lane & 15;
  const int hi = lane >> 4;
  const int sw = (lr >> 1) & 3;
  const int kof0 = ((((hi >> 1)) ^ sw) << 4) + (hi & 1) * 8;
  const int kof1 = (((2 + (hi >> 1)) ^ sw) << 4) + (hi & 1) * 8;
  const int rowA = (wm * 64 + lr) * 64;
  const int rowB = (wn * 64 + lr) * 64;
  const int NT = Kdim >> 6;

  async16(gA, lA + tid * 16);
  async16(gB, lB + tid * 16);
  async16(gB + (size_t)128 * Kdim, lB + 8192 + tid * 16);
  S_VM0();
  S_BAR();

  for (int t = 0; t < NT; ++t) {
    const int buf = t & 1;
    const char* pA = lA + buf * ASZ + rowA;
    const char* pB = lB + buf * BSZ + rowB;

    long a0[4], b0[4], a1[4], b1[4];
    #pragma unroll
    for (int ni = 0; ni < 4; ++ni) b0[ni] = *(const long*)(pB + ni * 1024 + kof0);
    #pragma unroll
    for (int mi = 0; mi < 4; ++mi) a0[mi] = *(const long*)(pA + mi * 1024 + kof0);
    SCHED_PIN();
    #pragma unroll
    for (int ni = 0; ni < 4; ++ni) b1[ni] = *(const long*)(pB + ni * 1024 + kof1);
    #pragma unroll
    for (int mi = 0; mi < 4; ++mi) a1[mi] = *(const long*)(pA + mi * 1024 + kof1);
    SCHED_PIN();
    if (t + 1 < NT) {
      const char* gAt = gA + (size_t)(t + 1) * 64;
      const char* gBt = gB + (size_t)(t + 1) * 64;
      char* lAd = lA + (buf ^ 1) * ASZ + tid * 16;
      char* lBd = lB + (buf ^ 1) * BSZ + tid * 16;
      async16(gAt, lAd);
      async16(gBt, lBd);
      async16(gBt + (size_t)128 * Kdim, lBd + 8192);
    }
    SCHED_PIN();
    __builtin_amdgcn_s_setprio(1);
    #pragma unroll
    for (int ni = 0; ni < 4; ++ni)
      #pragma unroll
      for (int mi = 0; mi < 4; ++mi)
        acc[ni][mi] = __builtin_amdgcn_mfma_f32_16x16x32_fp8_fp8(b0[ni], a0[mi], acc[ni][mi], 0, 0, 0);
    __builtin_amdgcn_s_setprio(0);
    SCHED_PIN();
    __builtin_amdgcn_s_setprio(1);
    #pragma unroll
    for (int ni = 0; ni < 4; ++ni)
      #pragma unroll
      for (int mi = 0; mi < 4; ++mi)
        acc[ni][mi] = __builtin_amdgcn_mfma_f32_16x16x32_fp8_fp8(b1[ni], a1[mi], acc[ni][mi], 0, 0, 0);
    __builtin_amdgcn_s_setprio(0);
    SCHED_PIN();
    if (t + 1 < NT) S_VM0();
    S_BAR();
  }

  #pragma unroll
  for (int p = 0; p < 2; ++p) {
    const int g = nblk * 8 + wn * 2 + p;
    const int cb = g * 16 + hi * 4;
    const bool isv = nblk >= 8;
    #pragma unroll
    for (int mf = 0; mf < 4; ++mf) {
      const int m = m0 + wm * 64 + mf * 16 + (lane & 15);
      float gg[4];
      #pragma unroll
      for (int r = 0; r < 4; ++r) {
        const float l = acc[2 * p][mf][r] * 0.0625f;
        const float q = acc[2 * p + 1][mf][r] * 0.0625f;
        gg[r] = l * 0.5f * q * (1.0f + erff(q * 0.70710678118f));
      }
      const u32 pk = pack4_e4m3(gg[0], gg[1], gg[2], gg[3]);
      if (isv) *(u32*)&vbuf8[(size_t)m * 1024 + (cb - 1024)] = pk;
      else     *(u32*)&fused8[(size_t)m * EDIM + cb] = pk;
    }
  }
}

// ---------------- fp8 project GEMM, 256 threads, BM=128 BN=128 BK=128 --------
__global__ __launch_bounds__(256, 2) void gemmproj(const char* __restrict__ A8,
                                                   const char* __restrict__ B8,
                                                   float* __restrict__ out,
                                                   const float* __restrict__ resid,
                                                   float scl) {
  constexpr int ASZ = 128 * 128;   // 16KB
  constexpr int BSZ = 128 * 128;   // 16KB
  constexpr int Kdim = 2048;
  __shared__ alignas(16) char As[2 * ASZ];
  __shared__ alignas(16) char Bs[2 * BSZ];

  const int tid = threadIdx.x;
  const int lane = tid & 63;
  const int w = tid >> 6;
  const int wm = w >> 1, wn = w & 1;

  const int qq = gridDim.x >> 3;
  const int wgid = (blockIdx.x & 7) * qq + (blockIdx.x >> 3);
  const int m0 = (wgid / 8) * 128;
  const int n0 = (wgid % 8) * 128;

  f32x4 acc[4][4] = {};

  const int rowS = tid >> 3;
  const int uS = tid & 7;
  const int luS = uS ^ (rowS & 7);
  const char* gA = A8 + (size_t)(m0 + rowS) * Kdim + luS * 16;
  const char* gB = B8 + (size_t)(n0 + rowS) * Kdim + luS * 16;
  char* lA = (char*)As;
  char* lB = (char*)Bs;

  const int lr = lane & 15;
  const int hi = lane >> 4;
  int kof[4];
  #pragma unroll
  for (int kq = 0; kq < 4; ++kq)
    kof[kq] = (((kq * 2 + (hi >> 1)) ^ (lr & 7)) << 4) + (hi & 1) * 8;
  const int rowA = (wm * 64 + lr) * 128;
  const int rowB = (wn * 64 + lr) * 128;
  const int NT = Kdim >> 7;            // 16

  #pragma unroll
  for (int c = 0; c < 4; ++c) {
    async16(gA + (size_t)c * 32 * Kdim, lA + c * 4096 + tid * 16);
    async16(gB + (size_t)c * 32 * Kdim, lB + c * 4096 + tid * 16);
  }
  S_VM0();
  S_BAR();

  for (int t = 0; t < NT; ++t) {
    const int buf = t & 1;
    const char* pA = lA + buf * ASZ + rowA;
    const char* pB = lB + buf * BSZ + rowB;

    long a[4][4], bb[4][4];
    #pragma unroll
    for (int kq = 0; kq < 4; ++kq) {
      #pragma unroll
      for (int ni = 0; ni < 4; ++ni) bb[kq][ni] = *(const long*)(pB + ni * 2048 + kof[kq]);
      #pragma unroll
      for (int mi = 0; mi < 4; ++mi) a[kq][mi] = *(const long*)(pA + mi * 2048 + kof[kq]);
    }
    SCHED_PIN();
    if (t + 1 < NT) {
      const char* gAt = gA + (size_t)(t + 1) * 128;
      const char* gBt = gB + (size_t)(t + 1) * 128;
      char* lAd = lA + (buf ^ 1) * ASZ + tid * 16;
      char* lBd = lB + (buf ^ 1) * BSZ + tid * 16;
      #pragma unroll
      for (int c = 0; c < 4; ++c) {
        async16(gAt + (size_t)c * 32 * Kdim, lAd + c * 4096);
        async16(gBt + (size_t)c * 32 * Kdim, lBd + c * 4096);
      }
    }
    SCHED_PIN();
    #pragma unroll
    for (int kq = 0; kq < 4; ++kq) {
      __builtin_amdgcn_s_setprio(1);
      #pragma unroll
      for (int mi = 0; mi < 4; ++mi)
        #pragma unroll
        for (int ni = 0; ni < 4; ++ni)
          acc[mi][ni] = __builtin_amdgcn_mfma_f32_16x16x32_fp8_fp8(a[kq][mi], bb[kq][ni], acc[mi][ni], 0, 0, 0);
      __builtin_amdgcn_s_setprio(0);
      SCHED_PIN();
    }
    if (t + 1 < NT) S_VM0();
    S_BAR();
  }

  #pragma unroll
  for (int mi = 0; mi < 4; ++mi) {
    const int rbase = m0 + wm * 64 + mi * 16 + (hi << 2);
    #pragma unroll
    for (int ni = 0; ni < 4; ++ni) {
      const int col = n0 + wn * 64 + ni * 16 + (lane & 15);
      #pragma unroll
      for (int r = 0; r < 4; ++r) {
        const size_t off = (size_t)(rbase + r) * DDIM + col;
        out[off] = resid[off] + acc[mi][ni][r] * scl;
      }
    }
  }
}

// --------- fp8 V transpose: vbuf8[8192][1024] -> vTb[b][h][sblk16][d256][s64] ------
__global__ __launch_bounds__(256) void vT8_kernel(const char* __restrict__ vbuf8,
                                                  char* __restrict__ vTb) {
  const int blk = blockIdx.x;          // 512
  const int sblk = blk & 15;
  const int head = (blk >> 4) & 3;
  const int b = blk >> 6;
  const int t = threadIdx.x;
  __shared__ u32 vt[64][66];

  const int s_l = t >> 2, q4 = t & 3;
  const uint4* src = (const uint4*)&vbuf8[(size_t)(b * 1024 + sblk * 64 + s_l) * 1024 +
                                          head * 256 + q4 * 64];
  #pragma unroll
  for (int c = 0; c < 4; ++c) {
    const uint4 ww = src[c];
    vt[s_l][q4 * 16 + c * 4 + 0] = ww.x;
    vt[s_l][q4 * 16 + c * 4 + 1] = ww.y;
    vt[s_l][q4 * 16 + c * 4 + 2] = ww.z;
    vt[s_l][q4 * 16 + c * 4 + 3] = ww.w;
  }
  __syncthreads();
  const int d = t;
  const int wsel = (d & 3) * 8;
  char* dst = vTb + (((size_t)(b * 4 + head) * 16 + sblk) * 256 + d) * 64;
  #pragma unroll
  for (int c = 0; c < 4; ++c) {
    u32 wo[4];
    #pragma unroll
    for (int k = 0; k < 4; ++k) {
      const int s0 = c * 16 + k * 4;
      const u32 r0 = vt[s0 + 0][d >> 2];
      const u32 r1 = vt[s0 + 1][d >> 2];
      const u32 r2 = vt[s0 + 2][d >> 2];
      const u32 r3 = vt[s0 + 3][d >> 2];
      wo[k] = ((r0 >> wsel) & 0xffu) | (((r1 >> wsel) & 0xffu) << 8) |
              (((r2 >> wsel) & 0xffu) << 16) | (((r3 >> wsel) & 0xffu) << 24);
    }
    *(uint4*)(dst + c * 16) = make_uint4(wo[0], wo[1], wo[2], wo[3]);
  }
}

// ------------- MFMA sliding-window attention (W=32) -------------
__global__ __launch_bounds__(256, 2) void attn_mfma(const __bf16* __restrict__ h,
                                                    const char* __restrict__ vTb,
                                                    char* __restrict__ fused8,
                                                    const float* __restrict__ pbm) {
  const int blk = blockIdx.x;          // 256
  const int qblk = blk & 7;
  const int head = (blk >> 3) & 3;
  const int b = blk >> 5;
  const int tid = threadIdx.x;
  const int lane = tid & 63;
  const int w = tid >> 6;
  __shared__ char vt[256 * 176];
  __shared__ char pl[4][32 * 80];

  const float p = pbm[0];
  const float sp = (p > 20.0f) ? p : log1pf(expf(p));

  {
    const int m = qblk * 2;
    const char* base = vTb + ((size_t)(b * 4 + head) * 16) * 16384;
    #pragma unroll
    for (int it = 0; it < 11; ++it) {
      const int U = it * 256 + tid;
      const int d = U / 11;
      const int slot = U - d * 11;
      int sb, so;
      if (slot >= 10)      { sb = m; so = 0; }
      else if (slot < 2)   { sb = m - 1; so = 32 + slot * 16; }
      else if (slot < 6)   { sb = m; so = (slot - 2) * 16; }
      else                 { sb = m + 1; so = (slot - 6) * 16; }
      if (sb < 0) sb = 0;
      async16(base + ((size_t)sb * 256 + d) * 64 + so, vt + U * 16);
    }
  }

  const int col = lane & 15;
  const int hi = lane >> 4;
  const int qb = qblk * 128 + w * 32;
  const int kb = qb - 32;

  f32x4 sc[4][2] = {};
  bf16x8 afr[4], bfr[2];
  #pragma unroll
  for (int mf = 0; mf < 4; ++mf) {
    int key = kb + mf * 16 + col;
    if (key < 0) key = 0;
    afr[mf] = *(const bf16x8*)&h[(size_t)(b * 1024 + key) * HQK + 128 + head * 32 + hi * 8];
  }
  #pragma unroll
  for (int nf = 0; nf < 2; ++nf)
    bfr[nf] = *(const bf16x8*)&h[(size_t)(b * 1024 + qb + nf * 16 + col) * HQK + head * 32 + hi * 8];
  #pragma unroll
  for (int mf = 0; mf < 4; ++mf)
    #pragma unroll
    for (int nf = 0; nf < 2; ++nf)
      sc[mf][nf] = __builtin_amdgcn_mfma_f32_16x16x32_bf16(afr[mf], bfr[nf], sc[mf][nf], 0, 0, 0);

  #pragma unroll
  for (int nf = 0; nf < 2; ++nf) {
    #pragma unroll
    for (int mf = 0; mf < 4; ++mf)
      #pragma unroll
      for (int r = 0; r < 4; ++r) {
        const int delta = mf * 16 + hi * 4 + r - nf * 16 - col - 32;
        const int keyabs = kb + mf * 16 + hi * 4 + r;
        const bool valid = (delta <= 0) & (delta >= -31) & (keyabs >= 0);
        sc[mf][nf][r] = valid ? sc[mf][nf][r] * 0.1767766953f + sp * (float)delta : -1e30f;
      }
    float m = -1e30f;
    #pragma unroll
    for (int mf = 0; mf < 4; ++mf)
      #pragma unroll
      for (int r = 0; r < 4; ++r) m = fmaxf(m, sc[mf][nf][r]);
    m = fmaxf(m, __shfl_xor(m, 16));
    m = fmaxf(m, __shfl_xor(m, 32));
    float s = 0.0f;
    #pragma unroll
    for (int mf = 0; mf < 4; ++mf)
      #pragma unroll
      for (int r = 0; r < 4; ++r) {
        const float e = __expf(sc[mf][nf][r] - m);
        sc[mf][nf][r] = e;
        s += e;
      }
    s += __shfl_xor(s, 16);
    s += __shfl_xor(s, 32);
    const float inv = 1.0f / s;
    #pragma unroll
    for (int mf = 0; mf < 4; ++mf) {
      const u32 pk = pack4_e4m3(sc[mf][nf][0] * inv, sc[mf][nf][1] * inv,
                                sc[mf][nf][2] * inv, sc[mf][nf][3] * inv);
      *(u32*)&pl[w][(nf * 16 + col) * 80 + mf * 16 + hi * 4] = pk;
    }
  }

  __syncthreads();

  const char* ppl = pl[w];
  const int kloc = w * 32;
  f32x4 ao[16][2] = {};
  #pragma unroll
  for (int kf = 0; kf < 2; ++kf) {
    long bfrag[2];
    #pragma unroll
    for (int nf = 0; nf < 2; ++nf)
      bfrag[nf] = *(const long*)&ppl[(nf * 16 + col) * 80 + kf * 32 + hi * 8];
    #pragma unroll
    for (int mf = 0; mf < 16; ++mf) {
      const long af = *(const long*)&vt[(mf * 16 + col) * 176 + kloc + kf * 32 + hi * 8];
      #pragma unroll
      for (int nf = 0; nf < 2; ++nf)
        ao[mf][nf] = __builtin_amdgcn_mfma_f32_16x16x32_fp8_fp8(af, bfrag[nf], ao[mf][nf], 0, 0, 0);
    }
  }

  #pragma unroll
  for (int mf = 0; mf < 16; ++mf)
    #pragma unroll
    for (int nf = 0; nf < 2; ++nf) {
      const u32 pk = pack4_e4m3(ao[mf][nf][0], ao[mf][nf][1], ao[mf][nf][2], ao[mf][nf][3]);
      *(u32*)&fused8[(size_t)(b * 1024 + qb + nf * 16 + col) * EDIM + 1024 +
                     head * 256 + mf * 16 + hi * 4] = pk;
    }
}

// ---------------- host launch ----------------
extern "C" void kernel_launch(void* const* d_in, const int* in_sizes, int n_in,
                              void* d_out, int out_size, void* d_ws, size_t ws_size,
                              hipStream_t stream) {
  const float* x = (const float*)d_in[0];
  const float* norm_w = (const float*)d_in[2];
  const float* expand_w = (const float*)d_in[3];
  const float* project_w = (const float*)d_in[4];
  const float* pbm = (const float*)d_in[5];
  float* out = (float*)d_out;

  char* ws = (char*)d_ws;
  u32*    xn8   = (u32*)(ws);                     //  8,388,608
  char*   wqk8  = (char*)(ws + 8388608);          //    262,144 (x16)
  char*   wexp8i= (char*)(ws + 8650752);          //  4,194,304 (interleaved, x16)
  char*   wproj8= (char*)(ws + 12845056);         //  2,097,152 (x256)
  __bf16* h     = (__bf16*)(ws + 14942208);       //  4,194,304 (q|k only)
  char*   fused8= (char*)(ws + 19136512);         // 16,777,216
  char*   vbuf8 = (char*)(ws + 35913728);         //  8,388,608
  char*   vTb   = (char*)(ws + 44302336);         //  8,388,608
  // total 52,690,944 bytes

  ln_kernel<<<MROWS, 256, 0, stream>>>(x, norm_w, xn8);
  cast8_kernel<<<256, 256, 0, stream>>>(expand_w, (u32*)wqk8, 65536, 16.0f);
  cast8i_kernel<<<4096, 256, 0, stream>>>(expand_w + 256 * DDIM, (u32*)wexp8i);
  cast8_kernel<<<2048, 256, 0, stream>>>(project_w, (u32*)wproj8, 524288, 256.0f);
  // q/k columns: M=8192, N=256, K=1024 fp8 -> 128 m x 2 n = 256 blocks
  gemmqk<<<256, 256, 0, stream>>>((const char*)xn8, wqk8, h);
  // expand + fused GEGLU: 64 m x 16 n = 1024 blocks, 512 threads (r11-proven)
  gemm1glu<<<1024, 512, 0, stream>>>((const char*)xn8, wexp8i, fused8, vbuf8);
  vT8_kernel<<<512, 256, 0, stream>>>(vbuf8, vTb);
  attn_mfma<<<256, 256, 0, stream>>>(h, vTb, fused8, pbm);
  // project: M=8192 (64 tiles) x N=1024 (8 tiles) = 512 blocks
  gemmproj<<<512, 256, 0, stream>>>(fused8, wproj8, out, x, 1.0f / 256.0f);
}